// Round 3
// baseline (811.265 us; speedup 1.0000x reference)
//
#include <hip/hip_runtime.h>

#define IN_DIM 128
#define OUT_DIM 64
#define NBUCK 782          // ceil(100000 / 128) row buckets
#define RPB 128            // rows per bucket (row >> 7)
#define CHUNK 4096         // edges per partition block

// ---------------------------------------------------------------------------
// Kernel 1: xw[n][c] = sum_k x[n][k] * W[k][c] + b[c]
// ---------------------------------------------------------------------------
__global__ __launch_bounds__(256) void gemm_xw_kernel(
    const float* __restrict__ x, const float* __restrict__ W,
    const float* __restrict__ b, float* __restrict__ xw, int n_nodes) {
    __shared__ float Ws[IN_DIM * OUT_DIM];   // 32 KB
    __shared__ float xs[4][IN_DIM];          // 2 KB

    const int tid  = threadIdx.x;
    const int lane = tid & 63;     // output channel
    const int rgrp = tid >> 6;     // 0..3 row within block-tile

    for (int i = tid; i < IN_DIM * OUT_DIM; i += 256) Ws[i] = W[i];
    const float bias = b[lane];

    for (int base = blockIdx.x * 4; base < n_nodes; base += gridDim.x * 4) {
        const int row = base + rgrp;
        __syncthreads();
        if (row < n_nodes) {
            xs[rgrp][lane]      = x[row * IN_DIM + lane];
            xs[rgrp][lane + 64] = x[row * IN_DIM + lane + 64];
        }
        __syncthreads();
        if (row < n_nodes) {
            float acc = bias;
            #pragma unroll
            for (int k = 0; k < IN_DIM; ++k)
                acc = fmaf(xs[rgrp][k], Ws[k * OUT_DIM + lane], acc);
            xw[row * OUT_DIM + lane] = acc;
        }
    }
}

// ---------------------------------------------------------------------------
// Kernel 2: global bucket histogram (LDS-aggregated). bcount pre-zeroed.
// ---------------------------------------------------------------------------
__global__ __launch_bounds__(256) void bucket_hist_kernel(
    const int* __restrict__ erow, int* __restrict__ bcount, int n_edges) {
    __shared__ int h[NBUCK];
    for (int i = threadIdx.x; i < NBUCK; i += 256) h[i] = 0;
    __syncthreads();
    const int stride = gridDim.x * blockDim.x;
    for (int e = blockIdx.x * blockDim.x + threadIdx.x; e < n_edges; e += stride)
        atomicAdd(&h[erow[e] >> 7], 1);
    __syncthreads();
    for (int i = threadIdx.x; i < NBUCK; i += 256)
        if (h[i]) atomicAdd(&bcount[i], h[i]);
}

// ---------------------------------------------------------------------------
// Kernel 3: exclusive scan of bucket counts (single block, 512 thr, 2/thr).
// Writes bbase[0..NBUCK] (bbase[NBUCK]=total) and cursor[i]=bbase[i].
// ---------------------------------------------------------------------------
__global__ __launch_bounds__(512) void bucket_scan_kernel(
    const int* __restrict__ bcount, int* __restrict__ bbase,
    int* __restrict__ cursor) {
    const int t = threadIdx.x;
    const int i0 = 2 * t, i1 = 2 * t + 1;
    int v0 = (i0 < NBUCK) ? bcount[i0] : 0;
    int v1 = (i1 < NBUCK) ? bcount[i1] : 0;
    const int s = v0 + v1;
    int inc = s;
    #pragma unroll
    for (int d = 1; d < 64; d <<= 1) {
        int u = __shfl_up(inc, d, 64);
        if ((t & 63) >= d) inc += u;
    }
    __shared__ int wsum[8];
    if ((t & 63) == 63) wsum[t >> 6] = inc;
    __syncthreads();
    int wp = 0;
    #pragma unroll
    for (int w = 0; w < 8; ++w) if (w < (t >> 6)) wp += wsum[w];
    const int ex = wp + (inc - s);
    if (i0 < NBUCK) { bbase[i0] = ex;      cursor[i0] = ex; }
    if (i1 < NBUCK) { bbase[i1] = ex + v0; cursor[i1] = ex + v0; }
    if (t == 511) bbase[NBUCK] = wp + inc;
}

// ---------------------------------------------------------------------------
// Kernel 4: partition edges into bucket-grouped ecs[] with run reservation.
// Per block: LDS hist of its 4096 edges -> LDS scan -> ONE global atomic per
// nonempty bucket to reserve a contiguous run -> stage edges in LDS sorted by
// bucket -> flush (near-sequential global writes).
// Payload packed: x = (rowlocal<<17) | col  (col < 131072), y = val bits.
// ---------------------------------------------------------------------------
__global__ __launch_bounds__(512) void partition_kernel(
    const int* __restrict__ erow, const int* __restrict__ ecol,
    const float* __restrict__ eval_, int* __restrict__ cursor,
    int2* __restrict__ ecs, int n_edges) {
    __shared__ int  hist[NBUCK];
    __shared__ int  lbase[NBUCK];    // scan result; reused as lcur in place-pass
    __shared__ int  gdelta[NBUCK];
    __shared__ int2 data[CHUNK];
    __shared__ int  gpos[CHUNK];
    __shared__ int  wsum[8];

    const int t = threadIdx.x;
    const int base = blockIdx.x * CHUNK;
    const int cnt = min(CHUNK, n_edges - base);

    for (int i = t; i < NBUCK; i += 512) hist[i] = 0;
    __syncthreads();

    int   myrow[CHUNK / 512];
    int   mycol[CHUNK / 512];
    float myval[CHUNK / 512];
    #pragma unroll
    for (int i = 0; i < CHUNK / 512; ++i) {
        const int idx = t + i * 512;
        if (idx < cnt) {
            const int e = base + idx;
            myrow[i] = erow[e];
            mycol[i] = ecol[e];
            myval[i] = eval_[e];
            atomicAdd(&hist[myrow[i] >> 7], 1);
        }
    }
    __syncthreads();

    // exclusive scan of hist (782 entries) -> lbase
    {
        const int i0 = 2 * t, i1 = 2 * t + 1;
        const int v0 = (i0 < NBUCK) ? hist[i0] : 0;
        const int v1 = (i1 < NBUCK) ? hist[i1] : 0;
        const int s = v0 + v1;
        int inc = s;
        #pragma unroll
        for (int d = 1; d < 64; d <<= 1) {
            int u = __shfl_up(inc, d, 64);
            if ((t & 63) >= d) inc += u;
        }
        if ((t & 63) == 63) wsum[t >> 6] = inc;
        __syncthreads();
        int wp = 0;
        #pragma unroll
        for (int w = 0; w < 8; ++w) if (w < (t >> 6)) wp += wsum[w];
        const int ex = wp + (inc - s);
        if (i0 < NBUCK) lbase[i0] = ex;
        if (i1 < NBUCK) lbase[i1] = ex + v0;
    }
    __syncthreads();

    // reserve global runs: gdelta[b] = global_run_base - local_base
    for (int i = t; i < NBUCK; i += 512) {
        const int c = hist[i];
        gdelta[i] = c ? (atomicAdd(&cursor[i], c) - lbase[i]) : 0;
    }
    __syncthreads();

    // place into LDS slots (lbase serves as running cursor)
    #pragma unroll
    for (int i = 0; i < CHUNK / 512; ++i) {
        const int idx = t + i * 512;
        if (idx < cnt) {
            const int bk = myrow[i] >> 7;
            const int slot = atomicAdd(&lbase[bk], 1);
            int2 p;
            p.x = ((myrow[i] & (RPB - 1)) << 17) | mycol[i];
            p.y = __float_as_int(myval[i]);
            data[slot] = p;
            gpos[slot] = slot + gdelta[bk];
        }
    }
    __syncthreads();

    // flush: consecutive slots -> consecutive positions within each run
    for (int slot = t; slot < cnt; slot += 512)
        ecs[gpos[slot]] = data[slot];
}

// ---------------------------------------------------------------------------
// Kernel 5: per-bucket aggregate with LDS fp32 atomics, fused ReLU store.
// One block (512 thr = 8 waves) per bucket; lane = output dim.
// ---------------------------------------------------------------------------
__global__ __launch_bounds__(512) void bucket_agg_kernel(
    const float* __restrict__ xw, const int2* __restrict__ ecs,
    const int* __restrict__ bbase, float* __restrict__ out, int n_nodes) {
    __shared__ float acc[RPB * OUT_DIM];   // 32 KB
    const int t    = threadIdx.x;
    const int lane = t & 63;
    const int wv   = t >> 6;               // 0..7
    const int bk   = blockIdx.x;

    for (int i = t; i < RPB * OUT_DIM; i += 512) acc[i] = 0.f;
    __syncthreads();

    const int start = bbase[bk];
    const int end   = bbase[bk + 1];

    // 2 edges in flight per wave for gather-latency hiding
    for (int e = start + wv * 2; e < end; e += 16) {
        const int2 p0 = ecs[e];
        const bool has1 = (e + 1 < end);
        const int2 p1 = has1 ? ecs[e + 1] : p0;

        const int   c0 = p0.x & 0x1FFFF;
        const int   r0 = p0.x >> 17;
        const float v0 = __int_as_float(p0.y);
        const float a0 = xw[(size_t)c0 * OUT_DIM + lane];

        const int   c1 = p1.x & 0x1FFFF;
        const int   r1 = p1.x >> 17;
        const float v1 = __int_as_float(p1.y);
        const float a1 = has1 ? xw[(size_t)c1 * OUT_DIM + lane] : 0.f;

        atomicAdd(&acc[r0 * OUT_DIM + lane], v0 * a0);
        if (has1) atomicAdd(&acc[r1 * OUT_DIM + lane], v1 * a1);
    }
    __syncthreads();

    const size_t outbase = (size_t)bk * RPB * OUT_DIM;
    const size_t outmax  = (size_t)n_nodes * OUT_DIM;
    for (int i = t; i < RPB * OUT_DIM; i += 512) {
        const size_t o = outbase + i;
        if (o < outmax) out[o] = fmaxf(acc[i], 0.f);
    }
}

// ---------------------------------------------------------------------------
// Fallback (ws too small): atomic scatter path.
// ---------------------------------------------------------------------------
__global__ __launch_bounds__(256) void edge_scatter_kernel(
    const float* __restrict__ xw, const int* __restrict__ erow,
    const int* __restrict__ ecol, const float* __restrict__ eval_,
    float* __restrict__ out, int n_edges) {
    const int lane  = threadIdx.x & 63;
    const int wid   = (blockIdx.x * blockDim.x + threadIdx.x) >> 6;
    const int nwave = (gridDim.x * blockDim.x) >> 6;
    for (int e = wid; e < n_edges; e += nwave) {
        const float m = eval_[e] * xw[(size_t)ecol[e] * OUT_DIM + lane];
        atomicAdd(&out[(size_t)erow[e] * OUT_DIM + lane], m);
    }
}

__global__ __launch_bounds__(256) void relu_kernel(float4* __restrict__ p, int n4) {
    const int stride = gridDim.x * blockDim.x;
    for (int i = blockIdx.x * blockDim.x + threadIdx.x; i < n4; i += stride) {
        float4 v = p[i];
        v.x = fmaxf(v.x, 0.f); v.y = fmaxf(v.y, 0.f);
        v.z = fmaxf(v.z, 0.f); v.w = fmaxf(v.w, 0.f);
        p[i] = v;
    }
}

extern "C" void kernel_launch(void* const* d_in, const int* in_sizes, int n_in,
                              void* d_out, int out_size, void* d_ws, size_t ws_size,
                              hipStream_t stream) {
    const float* x     = (const float*)d_in[0];
    const int*   erow  = (const int*)d_in[1];
    const int*   ecol  = (const int*)d_in[2];
    const float* eval_ = (const float*)d_in[3];
    const float* W     = (const float*)d_in[4];
    const float* b     = (const float*)d_in[5];
    float*       out   = (float*)d_out;

    const int n_nodes = in_sizes[0] / IN_DIM;
    const int n_edges = in_sizes[1];

    auto align256 = [](size_t v) { return (v + 255) & ~(size_t)255; };
    size_t off_xw     = 0;
    size_t off_bcount = align256(off_xw     + (size_t)n_nodes * OUT_DIM * 4);
    size_t off_bbase  = align256(off_bcount + (size_t)NBUCK * 4);
    size_t off_cursor = align256(off_bbase  + (size_t)(NBUCK + 1) * 4);
    size_t off_ecs    = align256(off_cursor + (size_t)NBUCK * 4);
    size_t need       = off_ecs + (size_t)n_edges * 8;

    float* xw = (float*)((char*)d_ws + off_xw);

    // 1) xw = x @ W + b
    gemm_xw_kernel<<<(n_nodes + 3) / 4, 256, 0, stream>>>(x, W, b, xw, n_nodes);

    if (need <= ws_size && n_nodes <= (1 << 17)) {
        int*  bcount = (int*)((char*)d_ws + off_bcount);
        int*  bbase  = (int*)((char*)d_ws + off_bbase);
        int*  cursor = (int*)((char*)d_ws + off_cursor);
        int2* ecs    = (int2*)((char*)d_ws + off_ecs);

        hipMemsetAsync(bcount, 0, (size_t)NBUCK * 4, stream);
        bucket_hist_kernel<<<512, 256, 0, stream>>>(erow, bcount, n_edges);
        bucket_scan_kernel<<<1, 512, 0, stream>>>(bcount, bbase, cursor);
        partition_kernel<<<(n_edges + CHUNK - 1) / CHUNK, 512, 0, stream>>>(
            erow, ecol, eval_, cursor, ecs, n_edges);
        bucket_agg_kernel<<<NBUCK, 512, 0, stream>>>(xw, ecs, bbase, out, n_nodes);
    } else {
        hipMemsetAsync(d_out, 0, (size_t)out_size * sizeof(float), stream);
        edge_scatter_kernel<<<8192, 256, 0, stream>>>(xw, erow, ecol, eval_, out, n_edges);
        relu_kernel<<<2048, 256, 0, stream>>>((float4*)d_out, out_size / 4);
    }
}

// Round 4
// 470.292 us; speedup vs baseline: 1.7250x; 1.7250x over previous
//
#include <hip/hip_runtime.h>
#include <limits.h>

#define IN_DIM 128
#define OUT_DIM 64
#define NBUCK 782          // ceil(100000 / 128) row buckets
#define RPB 128            // rows per bucket (row >> 7)
#define CHUNK 4096         // edges per partition block
#define SCAP 4096          // max edges per bucket for LDS sort (mean ~2046, 45 sigma)

// ---------------------------------------------------------------------------
// Kernel 1: xw[n][c] = sum_k x[n][k] * W[k][c] + b[c]
// W packed in LDS as float4 Wp[k4][c] (conflict-free ds_read_b128);
// 4 waves/block, each wave computes 4 rows/iter (W-read amortized 4x).
// ---------------------------------------------------------------------------
__global__ __launch_bounds__(256) void gemm_xw_kernel(
    const float* __restrict__ x, const float* __restrict__ W,
    const float* __restrict__ b, float* __restrict__ xw, int n_nodes) {
    __shared__ float4 Wp[32][64];   // 32 KB: Wp[k4][c] = W[4k4..4k4+3][c]
    __shared__ float4 xs[16][32];   // 8 KB: 16 rows x 128 k

    const int t    = threadIdx.x;
    const int lane = t & 63;        // output channel
    const int wv   = t >> 6;        // wave 0..3

    for (int i = t; i < 32 * 64; i += 256) {
        const int k4 = i >> 6, c = i & 63;
        Wp[k4][c] = make_float4(W[(4 * k4 + 0) * OUT_DIM + c],
                                W[(4 * k4 + 1) * OUT_DIM + c],
                                W[(4 * k4 + 2) * OUT_DIM + c],
                                W[(4 * k4 + 3) * OUT_DIM + c]);
    }
    const float bias = b[lane];
    const float4* x4 = (const float4*)x;   // one row = 32 float4

    for (int base = blockIdx.x * 16; base < n_nodes; base += gridDim.x * 16) {
        __syncthreads();
        for (int i = t; i < 16 * 32; i += 256) {
            const int rr = i >> 5, kk = i & 31;
            const int row = base + rr;
            xs[rr][kk] = (row < n_nodes) ? x4[(size_t)row * 32 + kk]
                                         : make_float4(0.f, 0.f, 0.f, 0.f);
        }
        __syncthreads();

        float acc0 = bias, acc1 = bias, acc2 = bias, acc3 = bias;
        const int rbase = wv * 4;
        #pragma unroll
        for (int k4 = 0; k4 < 32; ++k4) {
            const float4 w4 = Wp[k4][lane];
            const float4 a0 = xs[rbase + 0][k4];
            const float4 a1 = xs[rbase + 1][k4];
            const float4 a2 = xs[rbase + 2][k4];
            const float4 a3 = xs[rbase + 3][k4];
            acc0 = fmaf(a0.x, w4.x, fmaf(a0.y, w4.y, fmaf(a0.z, w4.z, fmaf(a0.w, w4.w, acc0))));
            acc1 = fmaf(a1.x, w4.x, fmaf(a1.y, w4.y, fmaf(a1.z, w4.z, fmaf(a1.w, w4.w, acc1))));
            acc2 = fmaf(a2.x, w4.x, fmaf(a2.y, w4.y, fmaf(a2.z, w4.z, fmaf(a2.w, w4.w, acc2))));
            acc3 = fmaf(a3.x, w4.x, fmaf(a3.y, w4.y, fmaf(a3.z, w4.z, fmaf(a3.w, w4.w, acc3))));
        }
        const int r0 = base + rbase;
        if (r0 + 0 < n_nodes) xw[(size_t)(r0 + 0) * OUT_DIM + lane] = acc0;
        if (r0 + 1 < n_nodes) xw[(size_t)(r0 + 1) * OUT_DIM + lane] = acc1;
        if (r0 + 2 < n_nodes) xw[(size_t)(r0 + 2) * OUT_DIM + lane] = acc2;
        if (r0 + 3 < n_nodes) xw[(size_t)(r0 + 3) * OUT_DIM + lane] = acc3;
    }
}

// ---------------------------------------------------------------------------
// Kernel 2: global bucket histogram (LDS-aggregated). bcount pre-zeroed.
// ---------------------------------------------------------------------------
__global__ __launch_bounds__(256) void bucket_hist_kernel(
    const int* __restrict__ erow, int* __restrict__ bcount, int n_edges) {
    __shared__ int h[NBUCK];
    for (int i = threadIdx.x; i < NBUCK; i += 256) h[i] = 0;
    __syncthreads();
    const int stride = gridDim.x * blockDim.x;
    for (int e = blockIdx.x * blockDim.x + threadIdx.x; e < n_edges; e += stride)
        atomicAdd(&h[erow[e] >> 7], 1);
    __syncthreads();
    for (int i = threadIdx.x; i < NBUCK; i += 256)
        if (h[i]) atomicAdd(&bcount[i], h[i]);
}

// ---------------------------------------------------------------------------
// Kernel 3: exclusive scan of bucket counts (single block, 512 thr, 2/thr).
// Writes bbase[0..NBUCK] (bbase[NBUCK]=total), cursor[i]=bbase[i], and
// row_ptr[n_nodes] = total edges (the CSR terminator).
// ---------------------------------------------------------------------------
__global__ __launch_bounds__(512) void bucket_scan_kernel(
    const int* __restrict__ bcount, int* __restrict__ bbase,
    int* __restrict__ cursor, int* __restrict__ row_ptr, int n_nodes) {
    const int t = threadIdx.x;
    const int i0 = 2 * t, i1 = 2 * t + 1;
    int v0 = (i0 < NBUCK) ? bcount[i0] : 0;
    int v1 = (i1 < NBUCK) ? bcount[i1] : 0;
    const int s = v0 + v1;
    int inc = s;
    #pragma unroll
    for (int d = 1; d < 64; d <<= 1) {
        int u = __shfl_up(inc, d, 64);
        if ((t & 63) >= d) inc += u;
    }
    __shared__ int wsum[8];
    if ((t & 63) == 63) wsum[t >> 6] = inc;
    __syncthreads();
    int wp = 0;
    #pragma unroll
    for (int w = 0; w < 8; ++w) if (w < (t >> 6)) wp += wsum[w];
    const int ex = wp + (inc - s);
    if (i0 < NBUCK) { bbase[i0] = ex;      cursor[i0] = ex; }
    if (i1 < NBUCK) { bbase[i1] = ex + v0; cursor[i1] = ex + v0; }
    if (t == 511) {
        bbase[NBUCK] = wp + inc;
        row_ptr[n_nodes] = wp + inc;
    }
}

// ---------------------------------------------------------------------------
// Kernel 4: partition edges into bucket-grouped ecs[] with run reservation.
// Payload packed: x = (rowlocal<<17) | col  (col < 131072), y = val bits.
// ---------------------------------------------------------------------------
__global__ __launch_bounds__(512) void partition_kernel(
    const int* __restrict__ erow, const int* __restrict__ ecol,
    const float* __restrict__ eval_, int* __restrict__ cursor,
    int2* __restrict__ ecs, int n_edges) {
    __shared__ int  hist[NBUCK];
    __shared__ int  lbase[NBUCK];
    __shared__ int  gdelta[NBUCK];
    __shared__ int2 data[CHUNK];
    __shared__ int  gpos[CHUNK];
    __shared__ int  wsum[8];

    const int t = threadIdx.x;
    const int base = blockIdx.x * CHUNK;
    const int cnt = min(CHUNK, n_edges - base);

    for (int i = t; i < NBUCK; i += 512) hist[i] = 0;
    __syncthreads();

    int   myrow[CHUNK / 512];
    int   mycol[CHUNK / 512];
    float myval[CHUNK / 512];
    #pragma unroll
    for (int i = 0; i < CHUNK / 512; ++i) {
        const int idx = t + i * 512;
        if (idx < cnt) {
            const int e = base + idx;
            myrow[i] = erow[e];
            mycol[i] = ecol[e];
            myval[i] = eval_[e];
            atomicAdd(&hist[myrow[i] >> 7], 1);
        }
    }
    __syncthreads();

    {
        const int i0 = 2 * t, i1 = 2 * t + 1;
        const int v0 = (i0 < NBUCK) ? hist[i0] : 0;
        const int v1 = (i1 < NBUCK) ? hist[i1] : 0;
        const int s = v0 + v1;
        int inc = s;
        #pragma unroll
        for (int d = 1; d < 64; d <<= 1) {
            int u = __shfl_up(inc, d, 64);
            if ((t & 63) >= d) inc += u;
        }
        if ((t & 63) == 63) wsum[t >> 6] = inc;
        __syncthreads();
        int wp = 0;
        #pragma unroll
        for (int w = 0; w < 8; ++w) if (w < (t >> 6)) wp += wsum[w];
        const int ex = wp + (inc - s);
        if (i0 < NBUCK) lbase[i0] = ex;
        if (i1 < NBUCK) lbase[i1] = ex + v0;
    }
    __syncthreads();

    for (int i = t; i < NBUCK; i += 512) {
        const int c = hist[i];
        gdelta[i] = c ? (atomicAdd(&cursor[i], c) - lbase[i]) : 0;
    }
    __syncthreads();

    #pragma unroll
    for (int i = 0; i < CHUNK / 512; ++i) {
        const int idx = t + i * 512;
        if (idx < cnt) {
            const int bk = myrow[i] >> 7;
            const int slot = atomicAdd(&lbase[bk], 1);
            int2 p;
            p.x = ((myrow[i] & (RPB - 1)) << 17) | mycol[i];
            p.y = __float_as_int(myval[i]);
            data[slot] = p;
            gpos[slot] = slot + gdelta[bk];
        }
    }
    __syncthreads();

    for (int slot = t; slot < cnt; slot += 512)
        ecs[gpos[slot]] = data[slot];
}

// ---------------------------------------------------------------------------
// Kernel 5: exact sort within each bucket run (in place via LDS), emitting
// CSR row_ptr. Int LDS atomics only. Overflow (cnt > SCAP, ~impossible for
// uniform rows) marks rows with INT_MIN; gather falls back to a filter scan.
// ---------------------------------------------------------------------------
__global__ __launch_bounds__(256) void sort_bucket_kernel(
    const int* __restrict__ bbase, int2* __restrict__ ecs,
    int* __restrict__ row_ptr, int n_nodes) {
    __shared__ int2 data[SCAP];    // 32 KB
    __shared__ int2 data2[SCAP];   // 32 KB
    __shared__ int  hist[RPB];
    __shared__ int  wtot;

    const int bk = blockIdx.x;
    const int t  = threadIdx.x;
    const int s  = bbase[bk];
    const int e  = bbase[bk + 1];
    const int cnt = e - s;
    const int rbase = bk * RPB;

    if (cnt > SCAP) {
        for (int r = t; r < RPB; r += 256)
            if (rbase + r < n_nodes) row_ptr[rbase + r] = INT_MIN;
        return;
    }

    for (int i = t; i < RPB; i += 256) hist[i] = 0;
    __syncthreads();

    for (int i = t; i < cnt; i += 256) {
        const int2 p = ecs[s + i];
        data[i] = p;
        atomicAdd(&hist[p.x >> 17], 1);
    }
    __syncthreads();

    // exclusive scan of hist[128] (waves 0 and 1)
    int inc = 0, v = 0;
    if (t < RPB) {
        v = hist[t];
        inc = v;
        #pragma unroll
        for (int d = 1; d < 64; d <<= 1) {
            int u = __shfl_up(inc, d, 64);
            if ((t & 63) >= d) inc += u;
        }
        if (t == 63) wtot = inc;
    }
    __syncthreads();
    if (t < RPB) {
        if (t >= 64) inc += wtot;
        const int ex = inc - v;
        if (rbase + t < n_nodes) row_ptr[rbase + t] = s + ex;
        hist[t] = ex;    // reuse as running cursor (base = exclusive prefix)
    }
    __syncthreads();

    for (int i = t; i < cnt; i += 256) {
        const int2 p = data[i];
        const int r = p.x >> 17;
        const int pos = atomicAdd(&hist[r], 1);
        data2[pos] = p;
    }
    __syncthreads();

    for (int i = t; i < cnt; i += 256) ecs[s + i] = data2[i];
}

// ---------------------------------------------------------------------------
// Kernel 6: gather-aggregate + ReLU. One 64-lane wave per row; lane = dim.
// 8 gathers in flight with predicated tail (no serial remainder).
// ---------------------------------------------------------------------------
__global__ __launch_bounds__(256) void gather_relu_kernel(
    const float* __restrict__ xw, const int2* __restrict__ ecs,
    const int* __restrict__ row_ptr, const int* __restrict__ bbase,
    float* __restrict__ out, int n_nodes, int n_edges) {
    const int lane = threadIdx.x & 63;
    const int r = (blockIdx.x * blockDim.x + threadIdx.x) >> 6;
    if (r >= n_nodes) return;

    const int s = row_ptr[r];
    float acc = 0.f;

    if (s == INT_MIN) {
        // overflow bucket: filter-scan the whole run
        const int bk = r >> 7;
        const int bs = bbase[bk], be = bbase[bk + 1];
        const int rl = r & (RPB - 1);
        for (int j = bs; j < be; ++j) {
            const int2 p = ecs[j];
            if ((p.x >> 17) == rl)
                acc = fmaf(__int_as_float(p.y),
                           xw[(size_t)(p.x & 0x1FFFF) * OUT_DIM + lane], acc);
        }
    } else {
        const int e2 = row_ptr[r + 1];
        const int e  = (e2 == INT_MIN) ? bbase[(r >> 7) + 1] : e2;
        for (int j = s; j < e; j += 8) {
            int2  p[8];
            float a[8];
            #pragma unroll
            for (int u = 0; u < 8; ++u) {
                const int idx = min(j + u, n_edges - 1);
                p[u] = ecs[idx];
            }
            #pragma unroll
            for (int u = 0; u < 8; ++u)
                a[u] = xw[(size_t)(p[u].x & 0x1FFFF) * OUT_DIM + lane];
            #pragma unroll
            for (int u = 0; u < 8; ++u)
                if (j + u < e) acc = fmaf(__int_as_float(p[u].y), a[u], acc);
        }
    }
    out[(size_t)r * OUT_DIM + lane] = fmaxf(acc, 0.f);
}

// ---------------------------------------------------------------------------
// Fallback (ws too small / size mismatch): atomic scatter path.
// ---------------------------------------------------------------------------
__global__ __launch_bounds__(256) void edge_scatter_kernel(
    const float* __restrict__ xw, const int* __restrict__ erow,
    const int* __restrict__ ecol, const float* __restrict__ eval_,
    float* __restrict__ out, int n_edges) {
    const int lane  = threadIdx.x & 63;
    const int wid   = (blockIdx.x * blockDim.x + threadIdx.x) >> 6;
    const int nwave = (gridDim.x * blockDim.x) >> 6;
    for (int e = wid; e < n_edges; e += nwave) {
        const float m = eval_[e] * xw[(size_t)ecol[e] * OUT_DIM + lane];
        atomicAdd(&out[(size_t)erow[e] * OUT_DIM + lane], m);
    }
}

__global__ __launch_bounds__(256) void relu_kernel(float4* __restrict__ p, int n4) {
    const int stride = gridDim.x * blockDim.x;
    for (int i = blockIdx.x * blockDim.x + threadIdx.x; i < n4; i += stride) {
        float4 v = p[i];
        v.x = fmaxf(v.x, 0.f); v.y = fmaxf(v.y, 0.f);
        v.z = fmaxf(v.z, 0.f); v.w = fmaxf(v.w, 0.f);
        p[i] = v;
    }
}

extern "C" void kernel_launch(void* const* d_in, const int* in_sizes, int n_in,
                              void* d_out, int out_size, void* d_ws, size_t ws_size,
                              hipStream_t stream) {
    const float* x     = (const float*)d_in[0];
    const int*   erow  = (const int*)d_in[1];
    const int*   ecol  = (const int*)d_in[2];
    const float* eval_ = (const float*)d_in[3];
    const float* W     = (const float*)d_in[4];
    const float* b     = (const float*)d_in[5];
    float*       out   = (float*)d_out;

    const int n_nodes = in_sizes[0] / IN_DIM;
    const int n_edges = in_sizes[1];

    auto align256 = [](size_t v) { return (v + 255) & ~(size_t)255; };
    size_t off_xw     = 0;
    size_t off_bcount = align256(off_xw     + (size_t)n_nodes * OUT_DIM * 4);
    size_t off_bbase  = align256(off_bcount + (size_t)NBUCK * 4);
    size_t off_cursor = align256(off_bbase  + (size_t)(NBUCK + 1) * 4);
    size_t off_rowptr = align256(off_cursor + (size_t)NBUCK * 4);
    size_t off_ecs    = align256(off_rowptr + (size_t)(n_nodes + 1) * 4);
    size_t need       = off_ecs + (size_t)n_edges * 8;

    float* xw = (float*)((char*)d_ws + off_xw);

    // 1) xw = x @ W + b
    gemm_xw_kernel<<<2048, 256, 0, stream>>>(x, W, b, xw, n_nodes);

    if (need <= ws_size && n_nodes <= NBUCK * RPB && n_edges > 0) {
        int*  bcount = (int*)((char*)d_ws + off_bcount);
        int*  bbase  = (int*)((char*)d_ws + off_bbase);
        int*  cursor = (int*)((char*)d_ws + off_cursor);
        int*  rowptr = (int*)((char*)d_ws + off_rowptr);
        int2* ecs    = (int2*)((char*)d_ws + off_ecs);

        hipMemsetAsync(bcount, 0, (size_t)NBUCK * 4, stream);
        bucket_hist_kernel<<<512, 256, 0, stream>>>(erow, bcount, n_edges);
        bucket_scan_kernel<<<1, 512, 0, stream>>>(bcount, bbase, cursor, rowptr, n_nodes);
        partition_kernel<<<(n_edges + CHUNK - 1) / CHUNK, 512, 0, stream>>>(
            erow, ecol, eval_, cursor, ecs, n_edges);
        sort_bucket_kernel<<<NBUCK, 256, 0, stream>>>(bbase, ecs, rowptr, n_nodes);
        gather_relu_kernel<<<(n_nodes + 3) / 4, 256, 0, stream>>>(
            xw, ecs, rowptr, bbase, out, n_nodes, n_edges);
    } else {
        hipMemsetAsync(d_out, 0, (size_t)out_size * sizeof(float), stream);
        edge_scatter_kernel<<<8192, 256, 0, stream>>>(xw, erow, ecol, eval_, out, n_edges);
        relu_kernel<<<2048, 256, 0, stream>>>((float4*)d_out, out_size / 4);
    }
}

// Round 5
// 174.261 us; speedup vs baseline: 4.6555x; 2.6988x over previous
//
#include <hip/hip_runtime.h>
#include <limits.h>

#define IN_DIM 128
#define OUT_DIM 64
#define NBUCK 782          // ceil(100000 / 128) row buckets
#define RPB 128            // rows per bucket (row >> 7)
#define CHUNK 4096         // edges per partition block
#define SCAP 4096          // max edges per bucket for LDS sort

// ---------------------------------------------------------------------------
// Kernel 1: xw[n][c] = sum_k x[n][k] * W[k][c] + b[c]
// W packed in LDS as float4 Wp[k4][c]; 2 rows per wave, unroll 4 to keep
// VGPR pressure low (round-4 lesson: 4 rows + full unroll => 256 VGPR + spill).
// ---------------------------------------------------------------------------
__global__ __launch_bounds__(256) void gemm_xw_kernel(
    const float* __restrict__ x, const float* __restrict__ W,
    const float* __restrict__ b, float* __restrict__ xw, int n_nodes) {
    __shared__ float4 Wp[32][64];   // 32 KB: Wp[k4][c] = W[4k4..4k4+3][c]
    __shared__ float4 xs[8][32];    // 4 KB: 8 rows x 128 k

    const int t    = threadIdx.x;
    const int lane = t & 63;        // output channel
    const int wv   = t >> 6;        // wave 0..3

    for (int i = t; i < 32 * 64; i += 256) {
        const int k4 = i >> 6, c = i & 63;
        Wp[k4][c] = make_float4(W[(4 * k4 + 0) * OUT_DIM + c],
                                W[(4 * k4 + 1) * OUT_DIM + c],
                                W[(4 * k4 + 2) * OUT_DIM + c],
                                W[(4 * k4 + 3) * OUT_DIM + c]);
    }
    const float bias = b[lane];
    const float4* x4 = (const float4*)x;   // one row = 32 float4

    for (int base = blockIdx.x * 8; base < n_nodes; base += gridDim.x * 8) {
        __syncthreads();
        for (int i = t; i < 8 * 32; i += 256) {
            const int rr = i >> 5, kk = i & 31;
            const int row = base + rr;
            xs[rr][kk] = (row < n_nodes) ? x4[(size_t)row * 32 + kk]
                                         : make_float4(0.f, 0.f, 0.f, 0.f);
        }
        __syncthreads();

        const int r0 = base + wv * 2;
        float acc0 = bias, acc1 = bias;
        #pragma unroll 4
        for (int k4 = 0; k4 < 32; ++k4) {
            const float4 w4 = Wp[k4][lane];
            const float4 a0 = xs[wv * 2 + 0][k4];
            const float4 a1 = xs[wv * 2 + 1][k4];
            acc0 = fmaf(a0.x, w4.x, fmaf(a0.y, w4.y, fmaf(a0.z, w4.z, fmaf(a0.w, w4.w, acc0))));
            acc1 = fmaf(a1.x, w4.x, fmaf(a1.y, w4.y, fmaf(a1.z, w4.z, fmaf(a1.w, w4.w, acc1))));
        }
        if (r0 + 0 < n_nodes) xw[(size_t)(r0 + 0) * OUT_DIM + lane] = acc0;
        if (r0 + 1 < n_nodes) xw[(size_t)(r0 + 1) * OUT_DIM + lane] = acc1;
    }
}

// ---------------------------------------------------------------------------
// Kernel 2: global bucket histogram (LDS-aggregated). bcount pre-zeroed.
// ---------------------------------------------------------------------------
__global__ __launch_bounds__(256) void bucket_hist_kernel(
    const int* __restrict__ erow, int* __restrict__ bcount, int n_edges) {
    __shared__ int h[NBUCK];
    for (int i = threadIdx.x; i < NBUCK; i += 256) h[i] = 0;
    __syncthreads();
    const int stride = gridDim.x * blockDim.x;
    for (int e = blockIdx.x * blockDim.x + threadIdx.x; e < n_edges; e += stride)
        atomicAdd(&h[erow[e] >> 7], 1);
    __syncthreads();
    for (int i = threadIdx.x; i < NBUCK; i += 256)
        if (h[i]) atomicAdd(&bcount[i], h[i]);
}

// ---------------------------------------------------------------------------
// Kernel 3: exclusive scan of bucket counts (single block, 512 thr, 2/thr).
// ---------------------------------------------------------------------------
__global__ __launch_bounds__(512) void bucket_scan_kernel(
    const int* __restrict__ bcount, int* __restrict__ bbase,
    int* __restrict__ cursor, int* __restrict__ row_ptr, int n_nodes) {
    const int t = threadIdx.x;
    const int i0 = 2 * t, i1 = 2 * t + 1;
    int v0 = (i0 < NBUCK) ? bcount[i0] : 0;
    int v1 = (i1 < NBUCK) ? bcount[i1] : 0;
    const int s = v0 + v1;
    int inc = s;
    #pragma unroll
    for (int d = 1; d < 64; d <<= 1) {
        int u = __shfl_up(inc, d, 64);
        if ((t & 63) >= d) inc += u;
    }
    __shared__ int wsum[8];
    if ((t & 63) == 63) wsum[t >> 6] = inc;
    __syncthreads();
    int wp = 0;
    #pragma unroll
    for (int w = 0; w < 8; ++w) if (w < (t >> 6)) wp += wsum[w];
    const int ex = wp + (inc - s);
    if (i0 < NBUCK) { bbase[i0] = ex;      cursor[i0] = ex; }
    if (i1 < NBUCK) { bbase[i1] = ex + v0; cursor[i1] = ex + v0; }
    if (t == 511) {
        bbase[NBUCK] = wp + inc;
        row_ptr[n_nodes] = wp + inc;
    }
}

// ---------------------------------------------------------------------------
// Kernel 4: partition edges into bucket-grouped ecs[] with run reservation.
// Payload packed: x = (rowlocal<<17) | col  (col < 131072), y = val bits.
// ---------------------------------------------------------------------------
__global__ __launch_bounds__(512) void partition_kernel(
    const int* __restrict__ erow, const int* __restrict__ ecol,
    const float* __restrict__ eval_, int* __restrict__ cursor,
    int2* __restrict__ ecs, int n_edges) {
    __shared__ int  hist[NBUCK];
    __shared__ int  lbase[NBUCK];
    __shared__ int  gdelta[NBUCK];
    __shared__ int2 data[CHUNK];
    __shared__ int  gpos[CHUNK];
    __shared__ int  wsum[8];

    const int t = threadIdx.x;
    const int base = blockIdx.x * CHUNK;
    const int cnt = min(CHUNK, n_edges - base);

    for (int i = t; i < NBUCK; i += 512) hist[i] = 0;
    __syncthreads();

    int   myrow[CHUNK / 512];
    int   mycol[CHUNK / 512];
    float myval[CHUNK / 512];
    #pragma unroll
    for (int i = 0; i < CHUNK / 512; ++i) {
        const int idx = t + i * 512;
        if (idx < cnt) {
            const int e = base + idx;
            myrow[i] = erow[e];
            mycol[i] = ecol[e];
            myval[i] = eval_[e];
            atomicAdd(&hist[myrow[i] >> 7], 1);
        }
    }
    __syncthreads();

    {
        const int i0 = 2 * t, i1 = 2 * t + 1;
        const int v0 = (i0 < NBUCK) ? hist[i0] : 0;
        const int v1 = (i1 < NBUCK) ? hist[i1] : 0;
        const int s = v0 + v1;
        int inc = s;
        #pragma unroll
        for (int d = 1; d < 64; d <<= 1) {
            int u = __shfl_up(inc, d, 64);
            if ((t & 63) >= d) inc += u;
        }
        if ((t & 63) == 63) wsum[t >> 6] = inc;
        __syncthreads();
        int wp = 0;
        #pragma unroll
        for (int w = 0; w < 8; ++w) if (w < (t >> 6)) wp += wsum[w];
        const int ex = wp + (inc - s);
        if (i0 < NBUCK) lbase[i0] = ex;
        if (i1 < NBUCK) lbase[i1] = ex + v0;
    }
    __syncthreads();

    for (int i = t; i < NBUCK; i += 512) {
        const int c = hist[i];
        gdelta[i] = c ? (atomicAdd(&cursor[i], c) - lbase[i]) : 0;
    }
    __syncthreads();

    #pragma unroll
    for (int i = 0; i < CHUNK / 512; ++i) {
        const int idx = t + i * 512;
        if (idx < cnt) {
            const int bk = myrow[i] >> 7;
            const int slot = atomicAdd(&lbase[bk], 1);
            int2 p;
            p.x = ((myrow[i] & (RPB - 1)) << 17) | mycol[i];
            p.y = __float_as_int(myval[i]);
            data[slot] = p;
            gpos[slot] = slot + gdelta[bk];
        }
    }
    __syncthreads();

    for (int slot = t; slot < cnt; slot += 512)
        ecs[gpos[slot]] = data[slot];
}

// ---------------------------------------------------------------------------
// Kernel 5: exact sort within each bucket run (in place via LDS), emitting
// CSR row_ptr. Overflow (cnt > SCAP) marks rows INT_MIN; gather filter-scans.
// ---------------------------------------------------------------------------
__global__ __launch_bounds__(256) void sort_bucket_kernel(
    const int* __restrict__ bbase, int2* __restrict__ ecs,
    int* __restrict__ row_ptr, int n_nodes) {
    __shared__ int2 data[SCAP];    // 32 KB
    __shared__ int2 data2[SCAP];   // 32 KB
    __shared__ int  hist[RPB];
    __shared__ int  wtot;

    const int bk = blockIdx.x;
    const int t  = threadIdx.x;
    const int s  = bbase[bk];
    const int e  = bbase[bk + 1];
    const int cnt = e - s;
    const int rbase = bk * RPB;

    if (cnt > SCAP) {
        for (int r = t; r < RPB; r += 256)
            if (rbase + r < n_nodes) row_ptr[rbase + r] = INT_MIN;
        return;
    }

    for (int i = t; i < RPB; i += 256) hist[i] = 0;
    __syncthreads();

    for (int i = t; i < cnt; i += 256) {
        const int2 p = ecs[s + i];
        data[i] = p;
        atomicAdd(&hist[p.x >> 17], 1);
    }
    __syncthreads();

    int inc = 0, v = 0;
    if (t < RPB) {
        v = hist[t];
        inc = v;
        #pragma unroll
        for (int d = 1; d < 64; d <<= 1) {
            int u = __shfl_up(inc, d, 64);
            if ((t & 63) >= d) inc += u;
        }
        if (t == 63) wtot = inc;
    }
    __syncthreads();
    if (t < RPB) {
        if (t >= 64) inc += wtot;
        const int ex = inc - v;
        if (rbase + t < n_nodes) row_ptr[rbase + t] = s + ex;
        hist[t] = ex;
    }
    __syncthreads();

    for (int i = t; i < cnt; i += 256) {
        const int2 p = data[i];
        const int r = p.x >> 17;
        const int pos = atomicAdd(&hist[r], 1);
        data2[pos] = p;
    }
    __syncthreads();

    for (int i = t; i < cnt; i += 256) ecs[s + i] = data2[i];
}

// ---------------------------------------------------------------------------
// Kernel 6: gather-aggregate + ReLU. One 64-lane wave per row; lane = dim.
// ---------------------------------------------------------------------------
__global__ __launch_bounds__(256) void gather_relu_kernel(
    const float* __restrict__ xw, const int2* __restrict__ ecs,
    const int* __restrict__ row_ptr, const int* __restrict__ bbase,
    float* __restrict__ out, int n_nodes, int n_edges) {
    const int lane = threadIdx.x & 63;
    const int r = (blockIdx.x * blockDim.x + threadIdx.x) >> 6;
    if (r >= n_nodes) return;

    const int s = row_ptr[r];
    float acc = 0.f;

    if (s == INT_MIN) {
        const int bk = r >> 7;
        const int bs = bbase[bk], be = bbase[bk + 1];
        const int rl = r & (RPB - 1);
        for (int j = bs; j < be; ++j) {
            const int2 p = ecs[j];
            if ((p.x >> 17) == rl)
                acc = fmaf(__int_as_float(p.y),
                           xw[(size_t)(p.x & 0x1FFFF) * OUT_DIM + lane], acc);
        }
    } else {
        const int e2 = row_ptr[r + 1];
        const int e  = (e2 == INT_MIN) ? bbase[(r >> 7) + 1] : e2;
        for (int j = s; j < e; j += 8) {
            int2  p[8];
            float a[8];
            #pragma unroll
            for (int u = 0; u < 8; ++u) {
                const int idx = min(j + u, n_edges - 1);
                p[u] = ecs[idx];
            }
            #pragma unroll
            for (int u = 0; u < 8; ++u)
                a[u] = xw[(size_t)(p[u].x & 0x1FFFF) * OUT_DIM + lane];
            #pragma unroll
            for (int u = 0; u < 8; ++u)
                if (j + u < e) acc = fmaf(__int_as_float(p[u].y), a[u], acc);
        }
    }
    out[(size_t)r * OUT_DIM + lane] = fmaxf(acc, 0.f);
}

// ---------------------------------------------------------------------------
// Fallback: atomic scatter path.
// ---------------------------------------------------------------------------
__global__ __launch_bounds__(256) void edge_scatter_kernel(
    const float* __restrict__ xw, const int* __restrict__ erow,
    const int* __restrict__ ecol, const float* __restrict__ eval_,
    float* __restrict__ out, int n_edges) {
    const int lane  = threadIdx.x & 63;
    const int wid   = (blockIdx.x * blockDim.x + threadIdx.x) >> 6;
    const int nwave = (gridDim.x * blockDim.x) >> 6;
    for (int e = wid; e < n_edges; e += nwave) {
        const float m = eval_[e] * xw[(size_t)ecol[e] * OUT_DIM + lane];
        atomicAdd(&out[(size_t)erow[e] * OUT_DIM + lane], m);
    }
}

__global__ __launch_bounds__(256) void relu_kernel(float4* __restrict__ p, int n4) {
    const int stride = gridDim.x * blockDim.x;
    for (int i = blockIdx.x * blockDim.x + threadIdx.x; i < n4; i += stride) {
        float4 v = p[i];
        v.x = fmaxf(v.x, 0.f); v.y = fmaxf(v.y, 0.f);
        v.z = fmaxf(v.z, 0.f); v.w = fmaxf(v.w, 0.f);
        p[i] = v;
    }
}

extern "C" void kernel_launch(void* const* d_in, const int* in_sizes, int n_in,
                              void* d_out, int out_size, void* d_ws, size_t ws_size,
                              hipStream_t stream) {
    const float* x     = (const float*)d_in[0];
    const int*   erow  = (const int*)d_in[1];
    const int*   ecol  = (const int*)d_in[2];
    const float* eval_ = (const float*)d_in[3];
    const float* W     = (const float*)d_in[4];
    const float* b     = (const float*)d_in[5];
    float*       out   = (float*)d_out;

    const int n_nodes = in_sizes[0] / IN_DIM;
    const int n_edges = in_sizes[1];

    auto align256 = [](size_t v) { return (v + 255) & ~(size_t)255; };
    size_t off_xw     = 0;
    size_t off_bcount = align256(off_xw     + (size_t)n_nodes * OUT_DIM * 4);
    size_t off_bbase  = align256(off_bcount + (size_t)NBUCK * 4);
    size_t off_cursor = align256(off_bbase  + (size_t)(NBUCK + 1) * 4);
    size_t off_rowptr = align256(off_cursor + (size_t)NBUCK * 4);
    size_t off_ecs    = align256(off_rowptr + (size_t)(n_nodes + 1) * 4);
    size_t need       = off_ecs + (size_t)n_edges * 8;

    float* xw = (float*)((char*)d_ws + off_xw);

    // 1) xw = x @ W + b
    gemm_xw_kernel<<<2048, 256, 0, stream>>>(x, W, b, xw, n_nodes);

    if (need <= ws_size && n_nodes <= NBUCK * RPB && n_edges > 0) {
        int*  bcount = (int*)((char*)d_ws + off_bcount);
        int*  bbase  = (int*)((char*)d_ws + off_bbase);
        int*  cursor = (int*)((char*)d_ws + off_cursor);
        int*  rowptr = (int*)((char*)d_ws + off_rowptr);
        int2* ecs    = (int2*)((char*)d_ws + off_ecs);

        hipMemsetAsync(bcount, 0, (size_t)NBUCK * 4, stream);
        bucket_hist_kernel<<<512, 256, 0, stream>>>(erow, bcount, n_edges);
        bucket_scan_kernel<<<1, 512, 0, stream>>>(bcount, bbase, cursor, rowptr, n_nodes);
        partition_kernel<<<(n_edges + CHUNK - 1) / CHUNK, 512, 0, stream>>>(
            erow, ecol, eval_, cursor, ecs, n_edges);
        sort_bucket_kernel<<<NBUCK, 256, 0, stream>>>(bbase, ecs, rowptr, n_nodes);
        gather_relu_kernel<<<(n_nodes + 3) / 4, 256, 0, stream>>>(
            xw, ecs, rowptr, bbase, out, n_nodes, n_edges);
    } else {
        hipMemsetAsync(d_out, 0, (size_t)out_size * sizeof(float), stream);
        edge_scatter_kernel<<<8192, 256, 0, stream>>>(xw, erow, ecol, eval_, out, n_edges);
        relu_kernel<<<2048, 256, 0, stream>>>((float4*)d_out, out_size / 4);
    }
}

// Round 6
// 173.818 us; speedup vs baseline: 4.6673x; 1.0025x over previous
//
#include <hip/hip_runtime.h>
#include <hip/hip_fp16.h>
#include <limits.h>

#define IN_DIM 128
#define OUT_DIM 64
#define NBUCK 782          // ceil(100000 / 128) row buckets
#define RPB 128            // rows per bucket (row >> 7)
#define CHUNK 4096         // edges per partition block
#define SCAP 4096          // max edges per bucket for LDS sort

// ---------------------------------------------------------------------------
// Kernel 1: xw[n][c] = (fp16) sum_k x[n][k] * W[k][c] + b[c]
// W packed in LDS as float4 Wp[k4][c]; 2 rows per wave, unroll 4 (round-4
// lesson: 4 rows + full unroll => 256 VGPR + scratch spill).
// xw stored fp16: halves the gather kernel's random-fetch bytes.
// ---------------------------------------------------------------------------
__global__ __launch_bounds__(256) void gemm_xw_kernel(
    const float* __restrict__ x, const float* __restrict__ W,
    const float* __restrict__ b, __half* __restrict__ xw, int n_nodes) {
    __shared__ float4 Wp[32][64];   // 32 KB: Wp[k4][c] = W[4k4..4k4+3][c]
    __shared__ float4 xs[8][32];    // 4 KB: 8 rows x 128 k

    const int t    = threadIdx.x;
    const int lane = t & 63;        // output channel
    const int wv   = t >> 6;        // wave 0..3

    for (int i = t; i < 32 * 64; i += 256) {
        const int k4 = i >> 6, c = i & 63;
        Wp[k4][c] = make_float4(W[(4 * k4 + 0) * OUT_DIM + c],
                                W[(4 * k4 + 1) * OUT_DIM + c],
                                W[(4 * k4 + 2) * OUT_DIM + c],
                                W[(4 * k4 + 3) * OUT_DIM + c]);
    }
    const float bias = b[lane];
    const float4* x4 = (const float4*)x;   // one row = 32 float4

    for (int base = blockIdx.x * 8; base < n_nodes; base += gridDim.x * 8) {
        __syncthreads();
        for (int i = t; i < 8 * 32; i += 256) {
            const int rr = i >> 5, kk = i & 31;
            const int row = base + rr;
            xs[rr][kk] = (row < n_nodes) ? x4[(size_t)row * 32 + kk]
                                         : make_float4(0.f, 0.f, 0.f, 0.f);
        }
        __syncthreads();

        const int r0 = base + wv * 2;
        float acc0 = bias, acc1 = bias;
        #pragma unroll 4
        for (int k4 = 0; k4 < 32; ++k4) {
            const float4 w4 = Wp[k4][lane];
            const float4 a0 = xs[wv * 2 + 0][k4];
            const float4 a1 = xs[wv * 2 + 1][k4];
            acc0 = fmaf(a0.x, w4.x, fmaf(a0.y, w4.y, fmaf(a0.z, w4.z, fmaf(a0.w, w4.w, acc0))));
            acc1 = fmaf(a1.x, w4.x, fmaf(a1.y, w4.y, fmaf(a1.z, w4.z, fmaf(a1.w, w4.w, acc1))));
        }
        if (r0 + 0 < n_nodes) xw[(size_t)(r0 + 0) * OUT_DIM + lane] = __float2half(acc0);
        if (r0 + 1 < n_nodes) xw[(size_t)(r0 + 1) * OUT_DIM + lane] = __float2half(acc1);
    }
}

// ---------------------------------------------------------------------------
// Kernel 2: global bucket histogram (LDS-aggregated). bcount pre-zeroed.
// ---------------------------------------------------------------------------
__global__ __launch_bounds__(256) void bucket_hist_kernel(
    const int* __restrict__ erow, int* __restrict__ bcount, int n_edges) {
    __shared__ int h[NBUCK];
    for (int i = threadIdx.x; i < NBUCK; i += 256) h[i] = 0;
    __syncthreads();
    const int stride = gridDim.x * blockDim.x;
    for (int e = blockIdx.x * blockDim.x + threadIdx.x; e < n_edges; e += stride)
        atomicAdd(&h[erow[e] >> 7], 1);
    __syncthreads();
    for (int i = threadIdx.x; i < NBUCK; i += 256)
        if (h[i]) atomicAdd(&bcount[i], h[i]);
}

// ---------------------------------------------------------------------------
// Kernel 3: exclusive scan of bucket counts (single block, 512 thr, 2/thr).
// ---------------------------------------------------------------------------
__global__ __launch_bounds__(512) void bucket_scan_kernel(
    const int* __restrict__ bcount, int* __restrict__ bbase,
    int* __restrict__ cursor, int* __restrict__ row_ptr, int n_nodes) {
    const int t = threadIdx.x;
    const int i0 = 2 * t, i1 = 2 * t + 1;
    int v0 = (i0 < NBUCK) ? bcount[i0] : 0;
    int v1 = (i1 < NBUCK) ? bcount[i1] : 0;
    const int s = v0 + v1;
    int inc = s;
    #pragma unroll
    for (int d = 1; d < 64; d <<= 1) {
        int u = __shfl_up(inc, d, 64);
        if ((t & 63) >= d) inc += u;
    }
    __shared__ int wsum[8];
    if ((t & 63) == 63) wsum[t >> 6] = inc;
    __syncthreads();
    int wp = 0;
    #pragma unroll
    for (int w = 0; w < 8; ++w) if (w < (t >> 6)) wp += wsum[w];
    const int ex = wp + (inc - s);
    if (i0 < NBUCK) { bbase[i0] = ex;      cursor[i0] = ex; }
    if (i1 < NBUCK) { bbase[i1] = ex + v0; cursor[i1] = ex + v0; }
    if (t == 511) {
        bbase[NBUCK] = wp + inc;
        row_ptr[n_nodes] = wp + inc;
    }
}

// ---------------------------------------------------------------------------
// Kernel 4: partition edges into bucket-grouped ecs[] with run reservation.
// Payload packed: x = (rowlocal<<17) | col  (col < 131072), y = val bits.
// ---------------------------------------------------------------------------
__global__ __launch_bounds__(512) void partition_kernel(
    const int* __restrict__ erow, const int* __restrict__ ecol,
    const float* __restrict__ eval_, int* __restrict__ cursor,
    int2* __restrict__ ecs, int n_edges) {
    __shared__ int  hist[NBUCK];
    __shared__ int  lbase[NBUCK];
    __shared__ int  gdelta[NBUCK];
    __shared__ int2 data[CHUNK];
    __shared__ int  gpos[CHUNK];
    __shared__ int  wsum[8];

    const int t = threadIdx.x;
    const int base = blockIdx.x * CHUNK;
    const int cnt = min(CHUNK, n_edges - base);

    for (int i = t; i < NBUCK; i += 512) hist[i] = 0;
    __syncthreads();

    int   myrow[CHUNK / 512];
    int   mycol[CHUNK / 512];
    float myval[CHUNK / 512];
    #pragma unroll
    for (int i = 0; i < CHUNK / 512; ++i) {
        const int idx = t + i * 512;
        if (idx < cnt) {
            const int e = base + idx;
            myrow[i] = erow[e];
            mycol[i] = ecol[e];
            myval[i] = eval_[e];
            atomicAdd(&hist[myrow[i] >> 7], 1);
        }
    }
    __syncthreads();

    {
        const int i0 = 2 * t, i1 = 2 * t + 1;
        const int v0 = (i0 < NBUCK) ? hist[i0] : 0;
        const int v1 = (i1 < NBUCK) ? hist[i1] : 0;
        const int s = v0 + v1;
        int inc = s;
        #pragma unroll
        for (int d = 1; d < 64; d <<= 1) {
            int u = __shfl_up(inc, d, 64);
            if ((t & 63) >= d) inc += u;
        }
        if ((t & 63) == 63) wsum[t >> 6] = inc;
        __syncthreads();
        int wp = 0;
        #pragma unroll
        for (int w = 0; w < 8; ++w) if (w < (t >> 6)) wp += wsum[w];
        const int ex = wp + (inc - s);
        if (i0 < NBUCK) lbase[i0] = ex;
        if (i1 < NBUCK) lbase[i1] = ex + v0;
    }
    __syncthreads();

    for (int i = t; i < NBUCK; i += 512) {
        const int c = hist[i];
        gdelta[i] = c ? (atomicAdd(&cursor[i], c) - lbase[i]) : 0;
    }
    __syncthreads();

    #pragma unroll
    for (int i = 0; i < CHUNK / 512; ++i) {
        const int idx = t + i * 512;
        if (idx < cnt) {
            const int bk = myrow[i] >> 7;
            const int slot = atomicAdd(&lbase[bk], 1);
            int2 p;
            p.x = ((myrow[i] & (RPB - 1)) << 17) | mycol[i];
            p.y = __float_as_int(myval[i]);
            data[slot] = p;
            gpos[slot] = slot + gdelta[bk];
        }
    }
    __syncthreads();

    for (int slot = t; slot < cnt; slot += 512)
        ecs[gpos[slot]] = data[slot];
}

// ---------------------------------------------------------------------------
// Kernel 5: exact sort within each bucket run (in place via LDS), emitting
// CSR row_ptr. Overflow (cnt > SCAP) marks rows INT_MIN; gather filter-scans.
// ---------------------------------------------------------------------------
__global__ __launch_bounds__(256) void sort_bucket_kernel(
    const int* __restrict__ bbase, int2* __restrict__ ecs,
    int* __restrict__ row_ptr, int n_nodes) {
    __shared__ int2 data[SCAP];    // 32 KB
    __shared__ int2 data2[SCAP];   // 32 KB
    __shared__ int  hist[RPB];
    __shared__ int  wtot;

    const int bk = blockIdx.x;
    const int t  = threadIdx.x;
    const int s  = bbase[bk];
    const int e  = bbase[bk + 1];
    const int cnt = e - s;
    const int rbase = bk * RPB;

    if (cnt > SCAP) {
        for (int r = t; r < RPB; r += 256)
            if (rbase + r < n_nodes) row_ptr[rbase + r] = INT_MIN;
        return;
    }

    for (int i = t; i < RPB; i += 256) hist[i] = 0;
    __syncthreads();

    for (int i = t; i < cnt; i += 256) {
        const int2 p = ecs[s + i];
        data[i] = p;
        atomicAdd(&hist[p.x >> 17], 1);
    }
    __syncthreads();

    int inc = 0, v = 0;
    if (t < RPB) {
        v = hist[t];
        inc = v;
        #pragma unroll
        for (int d = 1; d < 64; d <<= 1) {
            int u = __shfl_up(inc, d, 64);
            if ((t & 63) >= d) inc += u;
        }
        if (t == 63) wtot = inc;
    }
    __syncthreads();
    if (t < RPB) {
        if (t >= 64) inc += wtot;
        const int ex = inc - v;
        if (rbase + t < n_nodes) row_ptr[rbase + t] = s + ex;
        hist[t] = ex;
    }
    __syncthreads();

    for (int i = t; i < cnt; i += 256) {
        const int2 p = data[i];
        const int r = p.x >> 17;
        const int pos = atomicAdd(&hist[r], 1);
        data2[pos] = p;
    }
    __syncthreads();

    for (int i = t; i < cnt; i += 256) ecs[s + i] = data2[i];
}

// ---------------------------------------------------------------------------
// Kernel 6: gather-aggregate + ReLU. One 64-lane wave per row; lane = dim.
// xw is fp16: 128 B per edge-gather instead of 256 B.
// ---------------------------------------------------------------------------
__global__ __launch_bounds__(256) void gather_relu_kernel(
    const __half* __restrict__ xw, const int2* __restrict__ ecs,
    const int* __restrict__ row_ptr, const int* __restrict__ bbase,
    float* __restrict__ out, int n_nodes, int n_edges) {
    const int lane = threadIdx.x & 63;
    const int r = (blockIdx.x * blockDim.x + threadIdx.x) >> 6;
    if (r >= n_nodes) return;

    const int s = row_ptr[r];
    float acc = 0.f;

    if (s == INT_MIN) {
        const int bk = r >> 7;
        const int bs = bbase[bk], be = bbase[bk + 1];
        const int rl = r & (RPB - 1);
        for (int j = bs; j < be; ++j) {
            const int2 p = ecs[j];
            if ((p.x >> 17) == rl)
                acc = fmaf(__int_as_float(p.y),
                           __half2float(xw[(size_t)(p.x & 0x1FFFF) * OUT_DIM + lane]), acc);
        }
    } else {
        const int e2 = row_ptr[r + 1];
        const int e  = (e2 == INT_MIN) ? bbase[(r >> 7) + 1] : e2;
        for (int j = s; j < e; j += 8) {
            int2  p[8];
            float a[8];
            #pragma unroll
            for (int u = 0; u < 8; ++u) {
                const int idx = min(j + u, n_edges - 1);
                p[u] = ecs[idx];
            }
            #pragma unroll
            for (int u = 0; u < 8; ++u)
                a[u] = __half2float(xw[(size_t)(p[u].x & 0x1FFFF) * OUT_DIM + lane]);
            #pragma unroll
            for (int u = 0; u < 8; ++u)
                if (j + u < e) acc = fmaf(__int_as_float(p[u].y), a[u], acc);
        }
    }
    out[(size_t)r * OUT_DIM + lane] = fmaxf(acc, 0.f);
}

// ---------------------------------------------------------------------------
// Fallback: atomic scatter path.
// ---------------------------------------------------------------------------
__global__ __launch_bounds__(256) void edge_scatter_kernel(
    const __half* __restrict__ xw, const int* __restrict__ erow,
    const int* __restrict__ ecol, const float* __restrict__ eval_,
    float* __restrict__ out, int n_edges) {
    const int lane  = threadIdx.x & 63;
    const int wid   = (blockIdx.x * blockDim.x + threadIdx.x) >> 6;
    const int nwave = (gridDim.x * blockDim.x) >> 6;
    for (int e = wid; e < n_edges; e += nwave) {
        const float m = eval_[e] * __half2float(xw[(size_t)ecol[e] * OUT_DIM + lane]);
        atomicAdd(&out[(size_t)erow[e] * OUT_DIM + lane], m);
    }
}

__global__ __launch_bounds__(256) void relu_kernel(float4* __restrict__ p, int n4) {
    const int stride = gridDim.x * blockDim.x;
    for (int i = blockIdx.x * blockDim.x + threadIdx.x; i < n4; i += stride) {
        float4 v = p[i];
        v.x = fmaxf(v.x, 0.f); v.y = fmaxf(v.y, 0.f);
        v.z = fmaxf(v.z, 0.f); v.w = fmaxf(v.w, 0.f);
        p[i] = v;
    }
}

extern "C" void kernel_launch(void* const* d_in, const int* in_sizes, int n_in,
                              void* d_out, int out_size, void* d_ws, size_t ws_size,
                              hipStream_t stream) {
    const float* x     = (const float*)d_in[0];
    const int*   erow  = (const int*)d_in[1];
    const int*   ecol  = (const int*)d_in[2];
    const float* eval_ = (const float*)d_in[3];
    const float* W     = (const float*)d_in[4];
    const float* b     = (const float*)d_in[5];
    float*       out   = (float*)d_out;

    const int n_nodes = in_sizes[0] / IN_DIM;
    const int n_edges = in_sizes[1];

    auto align256 = [](size_t v) { return (v + 255) & ~(size_t)255; };
    size_t off_xw     = 0;
    size_t off_bcount = align256(off_xw     + (size_t)n_nodes * OUT_DIM * 2); // fp16
    size_t off_bbase  = align256(off_bcount + (size_t)NBUCK * 4);
    size_t off_cursor = align256(off_bbase  + (size_t)(NBUCK + 1) * 4);
    size_t off_rowptr = align256(off_cursor + (size_t)NBUCK * 4);
    size_t off_ecs    = align256(off_rowptr + (size_t)(n_nodes + 1) * 4);
    size_t need       = off_ecs + (size_t)n_edges * 8;

    __half* xw = (__half*)((char*)d_ws + off_xw);

    // 1) xw = x @ W + b  (fp16 intermediate)
    gemm_xw_kernel<<<2048, 256, 0, stream>>>(x, W, b, xw, n_nodes);

    if (need <= ws_size && n_nodes <= NBUCK * RPB && n_edges > 0) {
        int*  bcount = (int*)((char*)d_ws + off_bcount);
        int*  bbase  = (int*)((char*)d_ws + off_bbase);
        int*  cursor = (int*)((char*)d_ws + off_cursor);
        int*  rowptr = (int*)((char*)d_ws + off_rowptr);
        int2* ecs    = (int2*)((char*)d_ws + off_ecs);

        hipMemsetAsync(bcount, 0, (size_t)NBUCK * 4, stream);
        bucket_hist_kernel<<<512, 256, 0, stream>>>(erow, bcount, n_edges);
        bucket_scan_kernel<<<1, 512, 0, stream>>>(bcount, bbase, cursor, rowptr, n_nodes);
        partition_kernel<<<(n_edges + CHUNK - 1) / CHUNK, 512, 0, stream>>>(
            erow, ecol, eval_, cursor, ecs, n_edges);
        sort_bucket_kernel<<<NBUCK, 256, 0, stream>>>(bbase, ecs, rowptr, n_nodes);
        gather_relu_kernel<<<(n_nodes + 3) / 4, 256, 0, stream>>>(
            xw, ecs, rowptr, bbase, out, n_nodes, n_edges);
    } else {
        hipMemsetAsync(d_out, 0, (size_t)out_size * sizeof(float), stream);
        edge_scatter_kernel<<<8192, 256, 0, stream>>>(xw, erow, ecol, eval_, out, n_edges);
        relu_kernel<<<2048, 256, 0, stream>>>((float4*)d_out, out_size / 4);
    }
}

// Round 7
// 147.740 us; speedup vs baseline: 5.4912x; 1.1765x over previous
//
#include <hip/hip_runtime.h>
#include <hip/hip_fp16.h>
#include <limits.h>

#define IN_DIM 128
#define OUT_DIM 64
#define NBUCK 782          // ceil(100000 / 128) row buckets
#define RPB 128            // rows per bucket (row >> 7)
#define CHUNK 4096         // edges per partition block
#define SCAP 4096          // max edges per bucket for LDS sort

// ---------------------------------------------------------------------------
// Kernel 1: xw[n][c] = (fp16) sum_k x[n][k] * W[k][c] + b[c]
// ---------------------------------------------------------------------------
__global__ __launch_bounds__(256) void gemm_xw_kernel(
    const float* __restrict__ x, const float* __restrict__ W,
    const float* __restrict__ b, __half* __restrict__ xw, int n_nodes) {
    __shared__ float4 Wp[32][64];   // 32 KB
    __shared__ float4 xs[8][32];    // 4 KB

    const int t    = threadIdx.x;
    const int lane = t & 63;
    const int wv   = t >> 6;

    for (int i = t; i < 32 * 64; i += 256) {
        const int k4 = i >> 6, c = i & 63;
        Wp[k4][c] = make_float4(W[(4 * k4 + 0) * OUT_DIM + c],
                                W[(4 * k4 + 1) * OUT_DIM + c],
                                W[(4 * k4 + 2) * OUT_DIM + c],
                                W[(4 * k4 + 3) * OUT_DIM + c]);
    }
    const float bias = b[lane];
    const float4* x4 = (const float4*)x;

    for (int base = blockIdx.x * 8; base < n_nodes; base += gridDim.x * 8) {
        __syncthreads();
        for (int i = t; i < 8 * 32; i += 256) {
            const int rr = i >> 5, kk = i & 31;
            const int row = base + rr;
            xs[rr][kk] = (row < n_nodes) ? x4[(size_t)row * 32 + kk]
                                         : make_float4(0.f, 0.f, 0.f, 0.f);
        }
        __syncthreads();

        const int r0 = base + wv * 2;
        float acc0 = bias, acc1 = bias;
        #pragma unroll 4
        for (int k4 = 0; k4 < 32; ++k4) {
            const float4 w4 = Wp[k4][lane];
            const float4 a0 = xs[wv * 2 + 0][k4];
            const float4 a1 = xs[wv * 2 + 1][k4];
            acc0 = fmaf(a0.x, w4.x, fmaf(a0.y, w4.y, fmaf(a0.z, w4.z, fmaf(a0.w, w4.w, acc0))));
            acc1 = fmaf(a1.x, w4.x, fmaf(a1.y, w4.y, fmaf(a1.z, w4.z, fmaf(a1.w, w4.w, acc1))));
        }
        if (r0 + 0 < n_nodes) xw[(size_t)(r0 + 0) * OUT_DIM + lane] = __float2half(acc0);
        if (r0 + 1 < n_nodes) xw[(size_t)(r0 + 1) * OUT_DIM + lane] = __float2half(acc1);
    }
}

// ---------------------------------------------------------------------------
// Kernel 2: global bucket histogram (LDS-aggregated). bcount pre-zeroed.
// ---------------------------------------------------------------------------
__global__ __launch_bounds__(256) void bucket_hist_kernel(
    const int* __restrict__ erow, int* __restrict__ bcount, int n_edges) {
    __shared__ int h[NBUCK];
    for (int i = threadIdx.x; i < NBUCK; i += 256) h[i] = 0;
    __syncthreads();
    const int stride = gridDim.x * blockDim.x;
    for (int e = blockIdx.x * blockDim.x + threadIdx.x; e < n_edges; e += stride)
        atomicAdd(&h[erow[e] >> 7], 1);
    __syncthreads();
    for (int i = threadIdx.x; i < NBUCK; i += 256)
        if (h[i]) atomicAdd(&bcount[i], h[i]);
}

// ---------------------------------------------------------------------------
// Kernel 3: exclusive scan of bucket counts (single block, 512 thr, 2/thr).
// ---------------------------------------------------------------------------
__global__ __launch_bounds__(512) void bucket_scan_kernel(
    const int* __restrict__ bcount, int* __restrict__ bbase,
    int* __restrict__ cursor, int* __restrict__ row_ptr, int n_nodes) {
    const int t = threadIdx.x;
    const int i0 = 2 * t, i1 = 2 * t + 1;
    int v0 = (i0 < NBUCK) ? bcount[i0] : 0;
    int v1 = (i1 < NBUCK) ? bcount[i1] : 0;
    const int s = v0 + v1;
    int inc = s;
    #pragma unroll
    for (int d = 1; d < 64; d <<= 1) {
        int u = __shfl_up(inc, d, 64);
        if ((t & 63) >= d) inc += u;
    }
    __shared__ int wsum[8];
    if ((t & 63) == 63) wsum[t >> 6] = inc;
    __syncthreads();
    int wp = 0;
    #pragma unroll
    for (int w = 0; w < 8; ++w) if (w < (t >> 6)) wp += wsum[w];
    const int ex = wp + (inc - s);
    if (i0 < NBUCK) { bbase[i0] = ex;      cursor[i0] = ex; }
    if (i1 < NBUCK) { bbase[i1] = ex + v0; cursor[i1] = ex + v0; }
    if (t == 511) {
        bbase[NBUCK] = wp + inc;
        row_ptr[n_nodes] = wp + inc;
    }
}

// ---------------------------------------------------------------------------
// Kernel 4: partition edges into bucket-grouped ecs[] with run reservation.
// Payload packed: x = (rowlocal<<17) | col, y = val bits.
// ---------------------------------------------------------------------------
__global__ __launch_bounds__(512) void partition_kernel(
    const int* __restrict__ erow, const int* __restrict__ ecol,
    const float* __restrict__ eval_, int* __restrict__ cursor,
    int2* __restrict__ ecs, int n_edges) {
    __shared__ int  hist[NBUCK];
    __shared__ int  lbase[NBUCK];
    __shared__ int  gdelta[NBUCK];
    __shared__ int2 data[CHUNK];
    __shared__ int  gpos[CHUNK];
    __shared__ int  wsum[8];

    const int t = threadIdx.x;
    const int base = blockIdx.x * CHUNK;
    const int cnt = min(CHUNK, n_edges - base);

    for (int i = t; i < NBUCK; i += 512) hist[i] = 0;
    __syncthreads();

    int   myrow[CHUNK / 512];
    int   mycol[CHUNK / 512];
    float myval[CHUNK / 512];
    #pragma unroll
    for (int i = 0; i < CHUNK / 512; ++i) {
        const int idx = t + i * 512;
        if (idx < cnt) {
            const int e = base + idx;
            myrow[i] = erow[e];
            mycol[i] = ecol[e];
            myval[i] = eval_[e];
            atomicAdd(&hist[myrow[i] >> 7], 1);
        }
    }
    __syncthreads();

    {
        const int i0 = 2 * t, i1 = 2 * t + 1;
        const int v0 = (i0 < NBUCK) ? hist[i0] : 0;
        const int v1 = (i1 < NBUCK) ? hist[i1] : 0;
        const int s = v0 + v1;
        int inc = s;
        #pragma unroll
        for (int d = 1; d < 64; d <<= 1) {
            int u = __shfl_up(inc, d, 64);
            if ((t & 63) >= d) inc += u;
        }
        if ((t & 63) == 63) wsum[t >> 6] = inc;
        __syncthreads();
        int wp = 0;
        #pragma unroll
        for (int w = 0; w < 8; ++w) if (w < (t >> 6)) wp += wsum[w];
        const int ex = wp + (inc - s);
        if (i0 < NBUCK) lbase[i0] = ex;
        if (i1 < NBUCK) lbase[i1] = ex + v0;
    }
    __syncthreads();

    for (int i = t; i < NBUCK; i += 512) {
        const int c = hist[i];
        gdelta[i] = c ? (atomicAdd(&cursor[i], c) - lbase[i]) : 0;
    }
    __syncthreads();

    #pragma unroll
    for (int i = 0; i < CHUNK / 512; ++i) {
        const int idx = t + i * 512;
        if (idx < cnt) {
            const int bk = myrow[i] >> 7;
            const int slot = atomicAdd(&lbase[bk], 1);
            int2 p;
            p.x = ((myrow[i] & (RPB - 1)) << 17) | mycol[i];
            p.y = __float_as_int(myval[i]);
            data[slot] = p;
            gpos[slot] = slot + gdelta[bk];
        }
    }
    __syncthreads();

    for (int slot = t; slot < cnt; slot += 512)
        ecs[gpos[slot]] = data[slot];
}

// ---------------------------------------------------------------------------
// Kernel 5: exact sort within each bucket run (LDS), emitting CSR row_ptr.
// ---------------------------------------------------------------------------
__global__ __launch_bounds__(256) void sort_bucket_kernel(
    const int* __restrict__ bbase, int2* __restrict__ ecs,
    int* __restrict__ row_ptr, int n_nodes) {
    __shared__ int2 data[SCAP];    // 32 KB
    __shared__ int2 data2[SCAP];   // 32 KB
    __shared__ int  hist[RPB];
    __shared__ int  wtot;

    const int bk = blockIdx.x;
    const int t  = threadIdx.x;
    const int s  = bbase[bk];
    const int e  = bbase[bk + 1];
    const int cnt = e - s;
    const int rbase = bk * RPB;

    if (cnt > SCAP) {
        for (int r = t; r < RPB; r += 256)
            if (rbase + r < n_nodes) row_ptr[rbase + r] = INT_MIN;
        return;
    }

    for (int i = t; i < RPB; i += 256) hist[i] = 0;
    __syncthreads();

    for (int i = t; i < cnt; i += 256) {
        const int2 p = ecs[s + i];
        data[i] = p;
        atomicAdd(&hist[p.x >> 17], 1);
    }
    __syncthreads();

    int inc = 0, v = 0;
    if (t < RPB) {
        v = hist[t];
        inc = v;
        #pragma unroll
        for (int d = 1; d < 64; d <<= 1) {
            int u = __shfl_up(inc, d, 64);
            if ((t & 63) >= d) inc += u;
        }
        if (t == 63) wtot = inc;
    }
    __syncthreads();
    if (t < RPB) {
        if (t >= 64) inc += wtot;
        const int ex = inc - v;
        if (rbase + t < n_nodes) row_ptr[rbase + t] = s + ex;
        hist[t] = ex;
    }
    __syncthreads();

    for (int i = t; i < cnt; i += 256) {
        const int2 p = data[i];
        const int r = p.x >> 17;
        const int pos = atomicAdd(&hist[r], 1);
        data2[pos] = p;
    }
    __syncthreads();

    for (int i = t; i < cnt; i += 256) ecs[s + i] = data2[i];
}

// ---------------------------------------------------------------------------
// Kernel 6: gather-aggregate + ReLU, 2 edges per vmem instruction.
// One wave per row. Lanes 0-31 = even-step edges, lanes 32-63 = odd-step;
// each lane covers channel pair (2*pair, 2*pair+1) via half2 loads.
// 16-edge batches: 8 paired ecs loads + 8 paired half2 gathers in flight.
// Fold across halves with one shfl_xor(32); float2 coalesced store.
// ---------------------------------------------------------------------------
__global__ __launch_bounds__(256) void gather_relu_kernel(
    const __half* __restrict__ xw, const int2* __restrict__ ecs,
    const int* __restrict__ row_ptr, const int* __restrict__ bbase,
    float* __restrict__ out, int n_nodes, int n_edges) {
    const int lane = threadIdx.x & 63;
    const int pair = lane & 31;        // channel pair index
    const int h    = lane >> 5;        // half-wave: edge parity
    const int r = (blockIdx.x * blockDim.x + threadIdx.x) >> 6;
    if (r >= n_nodes) return;

    const int s = row_ptr[r];
    float ax = 0.f, ay = 0.f;
    const bool ovf = (s == INT_MIN);

    if (ovf) {
        // overflow bucket: filter-scan; both halves compute the full sum.
        const int bk = r >> 7;
        const int bs = bbase[bk], be = bbase[bk + 1];
        const int rl = r & (RPB - 1);
        for (int j = bs; j < be; ++j) {
            const int2 p = ecs[j];
            if ((p.x >> 17) == rl) {
                const __half2 a = *(const __half2*)(xw + (((size_t)(p.x & 0x1FFFF)) << 6) + 2 * pair);
                const float2 af = __half22float2(a);
                const float v = __int_as_float(p.y);
                ax = fmaf(v, af.x, ax);
                ay = fmaf(v, af.y, ay);
            }
        }
        // no fold: each half already holds the full row sum
    } else {
        const int e2 = row_ptr[r + 1];
        const int e  = (e2 == INT_MIN) ? bbase[(r >> 7) + 1] : e2;
        for (int j = s; j < e; j += 16) {
            int2 p[8];
            #pragma unroll
            for (int u = 0; u < 8; ++u) {
                const int eidx = j + 2 * u + h;
                p[u] = ecs[min(eidx, n_edges - 1)];
            }
            float  vv[8];
            float2 af[8];
            #pragma unroll
            for (int u = 0; u < 8; ++u) {
                const int eidx = j + 2 * u + h;
                vv[u] = (eidx < e) ? __int_as_float(p[u].y) : 0.f;
                af[u] = __half22float2(
                    *(const __half2*)(xw + (((size_t)(p[u].x & 0x1FFFF)) << 6) + 2 * pair));
            }
            #pragma unroll
            for (int u = 0; u < 8; ++u) {
                ax = fmaf(vv[u], af[u].x, ax);
                ay = fmaf(vv[u], af[u].y, ay);
            }
        }
        // fold: lane l and l+32 hold the same channel pair over disjoint edges
        ax += __shfl_xor(ax, 32, 64);
        ay += __shfl_xor(ay, 32, 64);
    }

    if (h == 0) {
        float2 o;
        o.x = fmaxf(ax, 0.f);
        o.y = fmaxf(ay, 0.f);
        *(float2*)(out + (size_t)r * OUT_DIM + 2 * pair) = o;
    }
}

// ---------------------------------------------------------------------------
// Fallback: atomic scatter path.
// ---------------------------------------------------------------------------
__global__ __launch_bounds__(256) void edge_scatter_kernel(
    const __half* __restrict__ xw, const int* __restrict__ erow,
    const int* __restrict__ ecol, const float* __restrict__ eval_,
    float* __restrict__ out, int n_edges) {
    const int lane  = threadIdx.x & 63;
    const int wid   = (blockIdx.x * blockDim.x + threadIdx.x) >> 6;
    const int nwave = (gridDim.x * blockDim.x) >> 6;
    for (int e = wid; e < n_edges; e += nwave) {
        const float m = eval_[e] * __half2float(xw[(size_t)ecol[e] * OUT_DIM + lane]);
        atomicAdd(&out[(size_t)erow[e] * OUT_DIM + lane], m);
    }
}

__global__ __launch_bounds__(256) void relu_kernel(float4* __restrict__ p, int n4) {
    const int stride = gridDim.x * blockDim.x;
    for (int i = blockIdx.x * blockDim.x + threadIdx.x; i < n4; i += stride) {
        float4 v = p[i];
        v.x = fmaxf(v.x, 0.f); v.y = fmaxf(v.y, 0.f);
        v.z = fmaxf(v.z, 0.f); v.w = fmaxf(v.w, 0.f);
        p[i] = v;
    }
}

extern "C" void kernel_launch(void* const* d_in, const int* in_sizes, int n_in,
                              void* d_out, int out_size, void* d_ws, size_t ws_size,
                              hipStream_t stream) {
    const float* x     = (const float*)d_in[0];
    const int*   erow  = (const int*)d_in[1];
    const int*   ecol  = (const int*)d_in[2];
    const float* eval_ = (const float*)d_in[3];
    const float* W     = (const float*)d_in[4];
    const float* b     = (const float*)d_in[5];
    float*       out   = (float*)d_out;

    const int n_nodes = in_sizes[0] / IN_DIM;
    const int n_edges = in_sizes[1];

    auto align256 = [](size_t v) { return (v + 255) & ~(size_t)255; };
    size_t off_xw     = 0;
    size_t off_bcount = align256(off_xw     + (size_t)n_nodes * OUT_DIM * 2); // fp16
    size_t off_bbase  = align256(off_bcount + (size_t)NBUCK * 4);
    size_t off_cursor = align256(off_bbase  + (size_t)(NBUCK + 1) * 4);
    size_t off_rowptr = align256(off_cursor + (size_t)NBUCK * 4);
    size_t off_ecs    = align256(off_rowptr + (size_t)(n_nodes + 1) * 4);
    size_t need       = off_ecs + (size_t)n_edges * 8;

    __half* xw = (__half*)((char*)d_ws + off_xw);

    // 1) xw = x @ W + b  (fp16 intermediate)
    gemm_xw_kernel<<<2048, 256, 0, stream>>>(x, W, b, xw, n_nodes);

    if (need <= ws_size && n_nodes <= NBUCK * RPB && n_edges > 0) {
        int*  bcount = (int*)((char*)d_ws + off_bcount);
        int*  bbase  = (int*)((char*)d_ws + off_bbase);
        int*  cursor = (int*)((char*)d_ws + off_cursor);
        int*  rowptr = (int*)((char*)d_ws + off_rowptr);
        int2* ecs    = (int2*)((char*)d_ws + off_ecs);

        hipMemsetAsync(bcount, 0, (size_t)NBUCK * 4, stream);
        bucket_hist_kernel<<<512, 256, 0, stream>>>(erow, bcount, n_edges);
        bucket_scan_kernel<<<1, 512, 0, stream>>>(bcount, bbase, cursor, rowptr, n_nodes);
        partition_kernel<<<(n_edges + CHUNK - 1) / CHUNK, 512, 0, stream>>>(
            erow, ecol, eval_, cursor, ecs, n_edges);
        sort_bucket_kernel<<<NBUCK, 256, 0, stream>>>(bbase, ecs, rowptr, n_nodes);
        gather_relu_kernel<<<(n_nodes + 3) / 4, 256, 0, stream>>>(
            xw, ecs, rowptr, bbase, out, n_nodes, n_edges);
    } else {
        hipMemsetAsync(d_out, 0, (size_t)out_size * sizeof(float), stream);
        edge_scatter_kernel<<<8192, 256, 0, stream>>>(xw, erow, ecol, eval_, out, n_edges);
        relu_kernel<<<2048, 256, 0, stream>>>((float4*)d_out, out_size / 4);
    }
}

// Round 8
// 124.651 us; speedup vs baseline: 6.5083x; 1.1852x over previous
//
#include <hip/hip_runtime.h>
#include <hip/hip_fp16.h>
#include <limits.h>

#define IN_DIM 128
#define OUT_DIM 64
#define NBUCK 782          // ceil(100000 / 128) row buckets
#define RPB 128            // rows per bucket (row >> 7)
#define CHUNK 4096         // edges per partition block
#define SCAP 4096          // max edges per bucket for LDS sort

typedef _Float16 half8_t __attribute__((ext_vector_type(8)));
typedef float    f32x4  __attribute__((ext_vector_type(4)));

// k-slot mapping used consistently for BOTH A and B fragment fills.
// (Any bijection of k works if used for both operands; dot products are
// permutation-invariant over k. C/D layout is the m89-verified one.)
__device__ __forceinline__ int kmap(int g, int j) {
    return g * 4 + (j & 3) + 16 * (j >> 2);   // g = lane>>4, j = elem 0..7
}

// ---------------------------------------------------------------------------
// Kernel 0: pre-pack W (fp32 [128][64]) into fragment-ordered fp16 blob:
// wf[((n*4 + ks)*64 + lane)*8 + j] = W[ks*32 + kmap(lane>>4, j)][n*16 + (lane&15)]
// ---------------------------------------------------------------------------
__global__ __launch_bounds__(256) void wfrag_kernel(
    const float* __restrict__ W, __half* __restrict__ wf) {
    for (int idx = threadIdx.x; idx < 4 * 4 * 64 * 8; idx += 256) {
        const int j    = idx & 7;
        const int lane = (idx >> 3) & 63;
        const int ks   = (idx >> 9) & 3;
        const int n    = idx >> 11;
        const int col  = n * 16 + (lane & 15);
        const int k    = ks * 32 + kmap(lane >> 4, j);
        wf[idx] = __float2half(W[k * OUT_DIM + col]);
    }
}

// ---------------------------------------------------------------------------
// Kernel 1: xw = fp16(x @ W + b) via MFMA 16x16x32 f16, no LDS.
// Block = 256 thr = 4 waves; each wave does 16 rows x 64 chans.
// A-frags loaded from global x (fp32->fp16 in regs), B-frags from wf (L2-hot).
// ---------------------------------------------------------------------------
__global__ __launch_bounds__(256) void gemm_mfma_kernel(
    const float* __restrict__ x, const __half* __restrict__ wf,
    const float* __restrict__ b, __half* __restrict__ xw, int n_nodes) {
    const int t  = threadIdx.x;
    const int l  = t & 63;
    const int wv = t >> 6;
    const int g  = l >> 4;
    const int rowbase = blockIdx.x * 64 + wv * 16;
    const int row = rowbase + (l & 15);
    const bool rok = row < n_nodes;
    const float* xr = x + (size_t)row * IN_DIM;

    // B fragments: 16 linear 16B lane-loads from the 16KB L2-hot blob
    half8_t bf[4][4];   // [n][ks]
    const half8_t* wf8 = (const half8_t*)wf;
    #pragma unroll
    for (int n = 0; n < 4; ++n)
        #pragma unroll
        for (int ks = 0; ks < 4; ++ks)
            bf[n][ks] = wf8[(n * 4 + ks) * 64 + l];

    // A fragments: two float4 chunks per ks (k = ks*32 + g*4 + {0..3, 16..19})
    half8_t af[4];
    #pragma unroll
    for (int ks = 0; ks < 4; ++ks) {
        float4 c0 = rok ? *(const float4*)(xr + ks * 32 + g * 4)
                        : make_float4(0.f, 0.f, 0.f, 0.f);
        float4 c1 = rok ? *(const float4*)(xr + ks * 32 + 16 + g * 4)
                        : make_float4(0.f, 0.f, 0.f, 0.f);
        half8_t a;
        a[0] = (_Float16)c0.x; a[1] = (_Float16)c0.y;
        a[2] = (_Float16)c0.z; a[3] = (_Float16)c0.w;
        a[4] = (_Float16)c1.x; a[5] = (_Float16)c1.y;
        a[6] = (_Float16)c1.z; a[7] = (_Float16)c1.w;
        af[ks] = a;
    }

    f32x4 acc[4];
    #pragma unroll
    for (int n = 0; n < 4; ++n) acc[n] = (f32x4){0.f, 0.f, 0.f, 0.f};

    #pragma unroll
    for (int ks = 0; ks < 4; ++ks)
        #pragma unroll
        for (int n = 0; n < 4; ++n)
            acc[n] = __builtin_amdgcn_mfma_f32_16x16x32_f16(af[ks], bf[n][ks], acc[n], 0, 0, 0);

    // bias per output column
    float bias[4];
    #pragma unroll
    for (int n = 0; n < 4; ++n) bias[n] = b[n * 16 + (l & 15)];

    // C/D layout (m89-verified): col = lane&15, row = (lane>>4)*4 + reg
    #pragma unroll
    for (int n = 0; n < 4; ++n)
        #pragma unroll
        for (int q = 0; q < 4; ++q) {
            const int ro = rowbase + g * 4 + q;
            if (ro < n_nodes)
                xw[(size_t)ro * OUT_DIM + n * 16 + (l & 15)] =
                    __float2half(acc[n][q] + bias[n]);
        }
}

// ---------------------------------------------------------------------------
// Kernel 2: global bucket histogram (LDS-aggregated). bcount pre-zeroed.
// ---------------------------------------------------------------------------
__global__ __launch_bounds__(256) void bucket_hist_kernel(
    const int* __restrict__ erow, int* __restrict__ bcount, int n_edges) {
    __shared__ int h[NBUCK];
    for (int i = threadIdx.x; i < NBUCK; i += 256) h[i] = 0;
    __syncthreads();
    const int stride = gridDim.x * blockDim.x;
    for (int e = blockIdx.x * blockDim.x + threadIdx.x; e < n_edges; e += stride)
        atomicAdd(&h[erow[e] >> 7], 1);
    __syncthreads();
    for (int i = threadIdx.x; i < NBUCK; i += 256)
        if (h[i]) atomicAdd(&bcount[i], h[i]);
}

// ---------------------------------------------------------------------------
// Kernel 3: exclusive scan of bucket counts (single block, 512 thr, 2/thr).
// ---------------------------------------------------------------------------
__global__ __launch_bounds__(512) void bucket_scan_kernel(
    const int* __restrict__ bcount, int* __restrict__ bbase,
    int* __restrict__ cursor, int* __restrict__ row_ptr, int n_nodes) {
    const int t = threadIdx.x;
    const int i0 = 2 * t, i1 = 2 * t + 1;
    int v0 = (i0 < NBUCK) ? bcount[i0] : 0;
    int v1 = (i1 < NBUCK) ? bcount[i1] : 0;
    const int s = v0 + v1;
    int inc = s;
    #pragma unroll
    for (int d = 1; d < 64; d <<= 1) {
        int u = __shfl_up(inc, d, 64);
        if ((t & 63) >= d) inc += u;
    }
    __shared__ int wsum[8];
    if ((t & 63) == 63) wsum[t >> 6] = inc;
    __syncthreads();
    int wp = 0;
    #pragma unroll
    for (int w = 0; w < 8; ++w) if (w < (t >> 6)) wp += wsum[w];
    const int ex = wp + (inc - s);
    if (i0 < NBUCK) { bbase[i0] = ex;      cursor[i0] = ex; }
    if (i1 < NBUCK) { bbase[i1] = ex + v0; cursor[i1] = ex + v0; }
    if (t == 511) {
        bbase[NBUCK] = wp + inc;
        row_ptr[n_nodes] = wp + inc;
    }
}

// ---------------------------------------------------------------------------
// Kernel 4: partition edges into bucket-grouped ecs[] with run reservation.
// Payload packed: x = (rowlocal<<17) | col, y = val bits.
// ---------------------------------------------------------------------------
__global__ __launch_bounds__(512) void partition_kernel(
    const int* __restrict__ erow, const int* __restrict__ ecol,
    const float* __restrict__ eval_, int* __restrict__ cursor,
    int2* __restrict__ ecs, int n_edges) {
    __shared__ int  hist[NBUCK];
    __shared__ int  lbase[NBUCK];
    __shared__ int  gdelta[NBUCK];
    __shared__ int2 data[CHUNK];
    __shared__ int  gpos[CHUNK];
    __shared__ int  wsum[8];

    const int t = threadIdx.x;
    const int base = blockIdx.x * CHUNK;
    const int cnt = min(CHUNK, n_edges - base);

    for (int i = t; i < NBUCK; i += 512) hist[i] = 0;
    __syncthreads();

    int   myrow[CHUNK / 512];
    int   mycol[CHUNK / 512];
    float myval[CHUNK / 512];
    #pragma unroll
    for (int i = 0; i < CHUNK / 512; ++i) {
        const int idx = t + i * 512;
        if (idx < cnt) {
            const int e = base + idx;
            myrow[i] = erow[e];
            mycol[i] = ecol[e];
            myval[i] = eval_[e];
            atomicAdd(&hist[myrow[i] >> 7], 1);
        }
    }
    __syncthreads();

    {
        const int i0 = 2 * t, i1 = 2 * t + 1;
        const int v0 = (i0 < NBUCK) ? hist[i0] : 0;
        const int v1 = (i1 < NBUCK) ? hist[i1] : 0;
        const int s = v0 + v1;
        int inc = s;
        #pragma unroll
        for (int d = 1; d < 64; d <<= 1) {
            int u = __shfl_up(inc, d, 64);
            if ((t & 63) >= d) inc += u;
        }
        if ((t & 63) == 63) wsum[t >> 6] = inc;
        __syncthreads();
        int wp = 0;
        #pragma unroll
        for (int w = 0; w < 8; ++w) if (w < (t >> 6)) wp += wsum[w];
        const int ex = wp + (inc - s);
        if (i0 < NBUCK) lbase[i0] = ex;
        if (i1 < NBUCK) lbase[i1] = ex + v0;
    }
    __syncthreads();

    for (int i = t; i < NBUCK; i += 512) {
        const int c = hist[i];
        gdelta[i] = c ? (atomicAdd(&cursor[i], c) - lbase[i]) : 0;
    }
    __syncthreads();

    #pragma unroll
    for (int i = 0; i < CHUNK / 512; ++i) {
        const int idx = t + i * 512;
        if (idx < cnt) {
            const int bk = myrow[i] >> 7;
            const int slot = atomicAdd(&lbase[bk], 1);
            int2 p;
            p.x = ((myrow[i] & (RPB - 1)) << 17) | mycol[i];
            p.y = __float_as_int(myval[i]);
            data[slot] = p;
            gpos[slot] = slot + gdelta[bk];
        }
    }
    __syncthreads();

    for (int slot = t; slot < cnt; slot += 512)
        ecs[gpos[slot]] = data[slot];
}

// ---------------------------------------------------------------------------
// Kernel 5: exact sort within each bucket run (LDS), emitting CSR row_ptr.
// ---------------------------------------------------------------------------
__global__ __launch_bounds__(256) void sort_bucket_kernel(
    const int* __restrict__ bbase, int2* __restrict__ ecs,
    int* __restrict__ row_ptr, int n_nodes) {
    __shared__ int2 data[SCAP];    // 32 KB
    __shared__ int2 data2[SCAP];   // 32 KB
    __shared__ int  hist[RPB];
    __shared__ int  wtot;

    const int bk = blockIdx.x;
    const int t  = threadIdx.x;
    const int s  = bbase[bk];
    const int e  = bbase[bk + 1];
    const int cnt = e - s;
    const int rbase = bk * RPB;

    if (cnt > SCAP) {
        for (int r = t; r < RPB; r += 256)
            if (rbase + r < n_nodes) row_ptr[rbase + r] = INT_MIN;
        return;
    }

    for (int i = t; i < RPB; i += 256) hist[i] = 0;
    __syncthreads();

    for (int i = t; i < cnt; i += 256) {
        const int2 p = ecs[s + i];
        data[i] = p;
        atomicAdd(&hist[p.x >> 17], 1);
    }
    __syncthreads();

    int inc = 0, v = 0;
    if (t < RPB) {
        v = hist[t];
        inc = v;
        #pragma unroll
        for (int d = 1; d < 64; d <<= 1) {
            int u = __shfl_up(inc, d, 64);
            if ((t & 63) >= d) inc += u;
        }
        if (t == 63) wtot = inc;
    }
    __syncthreads();
    if (t < RPB) {
        if (t >= 64) inc += wtot;
        const int ex = inc - v;
        if (rbase + t < n_nodes) row_ptr[rbase + t] = s + ex;
        hist[t] = ex;
    }
    __syncthreads();

    for (int i = t; i < cnt; i += 256) {
        const int2 p = data[i];
        const int r = p.x >> 17;
        const int pos = atomicAdd(&hist[r], 1);
        data2[pos] = p;
    }
    __syncthreads();

    for (int i = t; i < cnt; i += 256) ecs[s + i] = data2[i];
}

// ---------------------------------------------------------------------------
// Kernel 6: gather-aggregate + ReLU, 2 edges per vmem instruction.
// ---------------------------------------------------------------------------
__global__ __launch_bounds__(256) void gather_relu_kernel(
    const __half* __restrict__ xw, const int2* __restrict__ ecs,
    const int* __restrict__ row_ptr, const int* __restrict__ bbase,
    float* __restrict__ out, int n_nodes, int n_edges) {
    const int lane = threadIdx.x & 63;
    const int pair = lane & 31;        // channel pair index
    const int h    = lane >> 5;        // half-wave: edge parity
    const int r = (blockIdx.x * blockDim.x + threadIdx.x) >> 6;
    if (r >= n_nodes) return;

    const int s = row_ptr[r];
    float ax = 0.f, ay = 0.f;
    const bool ovf = (s == INT_MIN);

    if (ovf) {
        const int bk = r >> 7;
        const int bs = bbase[bk], be = bbase[bk + 1];
        const int rl = r & (RPB - 1);
        for (int j = bs; j < be; ++j) {
            const int2 p = ecs[j];
            if ((p.x >> 17) == rl) {
                const __half2 a = *(const __half2*)(xw + (((size_t)(p.x & 0x1FFFF)) << 6) + 2 * pair);
                const float2 af = __half22float2(a);
                const float v = __int_as_float(p.y);
                ax = fmaf(v, af.x, ax);
                ay = fmaf(v, af.y, ay);
            }
        }
    } else {
        const int e2 = row_ptr[r + 1];
        const int e  = (e2 == INT_MIN) ? bbase[(r >> 7) + 1] : e2;
        for (int j = s; j < e; j += 16) {
            int2 p[8];
            #pragma unroll
            for (int u = 0; u < 8; ++u) {
                const int eidx = j + 2 * u + h;
                p[u] = ecs[min(eidx, n_edges - 1)];
            }
            float  vv[8];
            float2 af[8];
            #pragma unroll
            for (int u = 0; u < 8; ++u) {
                const int eidx = j + 2 * u + h;
                vv[u] = (eidx < e) ? __int_as_float(p[u].y) : 0.f;
                af[u] = __half22float2(
                    *(const __half2*)(xw + (((size_t)(p[u].x & 0x1FFFF)) << 6) + 2 * pair));
            }
            #pragma unroll
            for (int u = 0; u < 8; ++u) {
                ax = fmaf(vv[u], af[u].x, ax);
                ay = fmaf(vv[u], af[u].y, ay);
            }
        }
        ax += __shfl_xor(ax, 32, 64);
        ay += __shfl_xor(ay, 32, 64);
    }

    if (h == 0) {
        float2 o;
        o.x = fmaxf(ax, 0.f);
        o.y = fmaxf(ay, 0.f);
        *(float2*)(out + (size_t)r * OUT_DIM + 2 * pair) = o;
    }
}

// ---------------------------------------------------------------------------
// Fallback: atomic scatter path.
// ---------------------------------------------------------------------------
__global__ __launch_bounds__(256) void edge_scatter_kernel(
    const __half* __restrict__ xw, const int* __restrict__ erow,
    const int* __restrict__ ecol, const float* __restrict__ eval_,
    float* __restrict__ out, int n_edges) {
    const int lane  = threadIdx.x & 63;
    const int wid   = (blockIdx.x * blockDim.x + threadIdx.x) >> 6;
    const int nwave = (gridDim.x * blockDim.x) >> 6;
    for (int e = wid; e < n_edges; e += nwave) {
        const float m = eval_[e] * __half2float(xw[(size_t)ecol[e] * OUT_DIM + lane]);
        atomicAdd(&out[(size_t)erow[e] * OUT_DIM + lane], m);
    }
}

__global__ __launch_bounds__(256) void relu_kernel(float4* __restrict__ p, int n4) {
    const int stride = gridDim.x * blockDim.x;
    for (int i = blockIdx.x * blockDim.x + threadIdx.x; i < n4; i += stride) {
        float4 v = p[i];
        v.x = fmaxf(v.x, 0.f); v.y = fmaxf(v.y, 0.f);
        v.z = fmaxf(v.z, 0.f); v.w = fmaxf(v.w, 0.f);
        p[i] = v;
    }
}

extern "C" void kernel_launch(void* const* d_in, const int* in_sizes, int n_in,
                              void* d_out, int out_size, void* d_ws, size_t ws_size,
                              hipStream_t stream) {
    const float* x     = (const float*)d_in[0];
    const int*   erow  = (const int*)d_in[1];
    const int*   ecol  = (const int*)d_in[2];
    const float* eval_ = (const float*)d_in[3];
    const float* W     = (const float*)d_in[4];
    const float* b     = (const float*)d_in[5];
    float*       out   = (float*)d_out;

    const int n_nodes = in_sizes[0] / IN_DIM;
    const int n_edges = in_sizes[1];

    auto align256 = [](size_t v) { return (v + 255) & ~(size_t)255; };
    size_t off_xw     = 0;
    size_t off_wf     = align256(off_xw     + (size_t)n_nodes * OUT_DIM * 2); // fp16 xw
    size_t off_bcount = align256(off_wf     + (size_t)4 * 4 * 64 * 8 * 2);    // fp16 W frags
    size_t off_bbase  = align256(off_bcount + (size_t)NBUCK * 4);
    size_t off_cursor = align256(off_bbase  + (size_t)(NBUCK + 1) * 4);
    size_t off_rowptr = align256(off_cursor + (size_t)NBUCK * 4);
    size_t off_ecs    = align256(off_rowptr + (size_t)(n_nodes + 1) * 4);
    size_t need       = off_ecs + (size_t)n_edges * 8;

    __half* xw = (__half*)((char*)d_ws + off_xw);
    __half* wf = (__half*)((char*)d_ws + off_wf);

    // 1) pre-pack W fragments, then xw = fp16(x @ W + b) via MFMA
    wfrag_kernel<<<1, 256, 0, stream>>>(W, wf);
    gemm_mfma_kernel<<<(n_nodes + 63) / 64, 256, 0, stream>>>(x, wf, b, xw, n_nodes);

    if (need <= ws_size && n_nodes <= NBUCK * RPB && n_edges > 0) {
        int*  bcount = (int*)((char*)d_ws + off_bcount);
        int*  bbase  = (int*)((char*)d_ws + off_bbase);
        int*  cursor = (int*)((char*)d_ws + off_cursor);
        int*  rowptr = (int*)((char*)d_ws + off_rowptr);
        int2* ecs    = (int2*)((char*)d_ws + off_ecs);

        hipMemsetAsync(bcount, 0, (size_t)NBUCK * 4, stream);
        bucket_hist_kernel<<<512, 256, 0, stream>>>(erow, bcount, n_edges);
        bucket_scan_kernel<<<1, 512, 0, stream>>>(bcount, bbase, cursor, rowptr, n_nodes);
        partition_kernel<<<(n_edges + CHUNK - 1) / CHUNK, 512, 0, stream>>>(
            erow, ecol, eval_, cursor, ecs, n_edges);
        sort_bucket_kernel<<<NBUCK, 256, 0, stream>>>(bbase, ecs, rowptr, n_nodes);
        gather_relu_kernel<<<(n_nodes + 3) / 4, 256, 0, stream>>>(
            xw, ecs, rowptr, bbase, out, n_nodes, n_edges);
    } else {
        hipMemsetAsync(d_out, 0, (size_t)out_size * sizeof(float), stream);
        edge_scatter_kernel<<<8192, 256, 0, stream>>>(xw, erow, ecol, eval_, out, n_edges);
        relu_kernel<<<2048, 256, 0, stream>>>((float4*)d_out, out_size / 4);
    }
}

// Round 9
// 122.961 us; speedup vs baseline: 6.5977x; 1.0137x over previous
//
#include <hip/hip_runtime.h>
#include <hip/hip_fp16.h>
#include <limits.h>

#define IN_DIM 128
#define OUT_DIM 64
#define NBUCK 782          // ceil(100000 / 128) row buckets
#define RPB 128            // rows per bucket (row >> 7)
#define CHUNK 4096         // edges per partition block
#define SCAP 4096          // max edges per bucket for LDS sort

// Payload packing (round 9): p.x = (rowlocal << 25) | (col << 7)
//  - col<<7 == col*128 == byte offset of row in fp16 xw  (col < 2^17, fits bits 7..24)
//  - rowlocal < 128 in bits 25..31 (extract with unsigned >> 25)
//  - gather lane address = (p.x & 0x01FFFF80) | (q << 4): single v_and_or_b32

typedef _Float16 half8_t __attribute__((ext_vector_type(8)));
typedef float    f32x4  __attribute__((ext_vector_type(4)));

// k-slot mapping used consistently for BOTH A and B fragment fills.
__device__ __forceinline__ int kmap(int g, int j) {
    return g * 4 + (j & 3) + 16 * (j >> 2);   // g = lane>>4, j = elem 0..7
}

// ---------------------------------------------------------------------------
// Kernel 0: pre-pack W (fp32 [128][64]) into fragment-ordered fp16 blob.
// ---------------------------------------------------------------------------
__global__ __launch_bounds__(256) void wfrag_kernel(
    const float* __restrict__ W, __half* __restrict__ wf) {
    for (int idx = threadIdx.x; idx < 4 * 4 * 64 * 8; idx += 256) {
        const int j    = idx & 7;
        const int lane = (idx >> 3) & 63;
        const int ks   = (idx >> 9) & 3;
        const int n    = idx >> 11;
        const int col  = n * 16 + (lane & 15);
        const int k    = ks * 32 + kmap(lane >> 4, j);
        wf[idx] = __float2half(W[k * OUT_DIM + col]);
    }
}

// ---------------------------------------------------------------------------
// Kernel 1: xw = fp16(x @ W + b) via MFMA 16x16x32 f16, no LDS.
// ---------------------------------------------------------------------------
__global__ __launch_bounds__(256) void gemm_mfma_kernel(
    const float* __restrict__ x, const __half* __restrict__ wf,
    const float* __restrict__ b, __half* __restrict__ xw, int n_nodes) {
    const int t  = threadIdx.x;
    const int l  = t & 63;
    const int wv = t >> 6;
    const int g  = l >> 4;
    const int rowbase = blockIdx.x * 64 + wv * 16;
    const int row = rowbase + (l & 15);
    const bool rok = row < n_nodes;
    const float* xr = x + (size_t)row * IN_DIM;

    half8_t bf[4][4];   // [n][ks]
    const half8_t* wf8 = (const half8_t*)wf;
    #pragma unroll
    for (int n = 0; n < 4; ++n)
        #pragma unroll
        for (int ks = 0; ks < 4; ++ks)
            bf[n][ks] = wf8[(n * 4 + ks) * 64 + l];

    half8_t af[4];
    #pragma unroll
    for (int ks = 0; ks < 4; ++ks) {
        float4 c0 = rok ? *(const float4*)(xr + ks * 32 + g * 4)
                        : make_float4(0.f, 0.f, 0.f, 0.f);
        float4 c1 = rok ? *(const float4*)(xr + ks * 32 + 16 + g * 4)
                        : make_float4(0.f, 0.f, 0.f, 0.f);
        half8_t a;
        a[0] = (_Float16)c0.x; a[1] = (_Float16)c0.y;
        a[2] = (_Float16)c0.z; a[3] = (_Float16)c0.w;
        a[4] = (_Float16)c1.x; a[5] = (_Float16)c1.y;
        a[6] = (_Float16)c1.z; a[7] = (_Float16)c1.w;
        af[ks] = a;
    }

    f32x4 acc[4];
    #pragma unroll
    for (int n = 0; n < 4; ++n) acc[n] = (f32x4){0.f, 0.f, 0.f, 0.f};

    #pragma unroll
    for (int ks = 0; ks < 4; ++ks)
        #pragma unroll
        for (int n = 0; n < 4; ++n)
            acc[n] = __builtin_amdgcn_mfma_f32_16x16x32_f16(af[ks], bf[n][ks], acc[n], 0, 0, 0);

    float bias[4];
    #pragma unroll
    for (int n = 0; n < 4; ++n) bias[n] = b[n * 16 + (l & 15)];

    // C/D layout (m89-verified): col = lane&15, row = (lane>>4)*4 + reg
    #pragma unroll
    for (int n = 0; n < 4; ++n)
        #pragma unroll
        for (int q = 0; q < 4; ++q) {
            const int ro = rowbase + g * 4 + q;
            if (ro < n_nodes)
                xw[(size_t)ro * OUT_DIM + n * 16 + (l & 15)] =
                    __float2half(acc[n][q] + bias[n]);
        }
}

// ---------------------------------------------------------------------------
// Kernel 2: global bucket histogram (LDS-aggregated). bcount pre-zeroed.
// ---------------------------------------------------------------------------
__global__ __launch_bounds__(256) void bucket_hist_kernel(
    const int* __restrict__ erow, int* __restrict__ bcount, int n_edges) {
    __shared__ int h[NBUCK];
    for (int i = threadIdx.x; i < NBUCK; i += 256) h[i] = 0;
    __syncthreads();
    const int stride = gridDim.x * blockDim.x;
    for (int e = blockIdx.x * blockDim.x + threadIdx.x; e < n_edges; e += stride)
        atomicAdd(&h[erow[e] >> 7], 1);
    __syncthreads();
    for (int i = threadIdx.x; i < NBUCK; i += 256)
        if (h[i]) atomicAdd(&bcount[i], h[i]);
}

// ---------------------------------------------------------------------------
// Kernel 3: exclusive scan of bucket counts (single block, 512 thr, 2/thr).
// ---------------------------------------------------------------------------
__global__ __launch_bounds__(512) void bucket_scan_kernel(
    const int* __restrict__ bcount, int* __restrict__ bbase,
    int* __restrict__ cursor, int* __restrict__ row_ptr, int n_nodes) {
    const int t = threadIdx.x;
    const int i0 = 2 * t, i1 = 2 * t + 1;
    int v0 = (i0 < NBUCK) ? bcount[i0] : 0;
    int v1 = (i1 < NBUCK) ? bcount[i1] : 0;
    const int s = v0 + v1;
    int inc = s;
    #pragma unroll
    for (int d = 1; d < 64; d <<= 1) {
        int u = __shfl_up(inc, d, 64);
        if ((t & 63) >= d) inc += u;
    }
    __shared__ int wsum[8];
    if ((t & 63) == 63) wsum[t >> 6] = inc;
    __syncthreads();
    int wp = 0;
    #pragma unroll
    for (int w = 0; w < 8; ++w) if (w < (t >> 6)) wp += wsum[w];
    const int ex = wp + (inc - s);
    if (i0 < NBUCK) { bbase[i0] = ex;      cursor[i0] = ex; }
    if (i1 < NBUCK) { bbase[i1] = ex + v0; cursor[i1] = ex + v0; }
    if (t == 511) {
        bbase[NBUCK] = wp + inc;
        row_ptr[n_nodes] = wp + inc;
    }
}

// ---------------------------------------------------------------------------
// Kernel 4: partition edges into bucket-grouped ecs[] with run reservation.
// ---------------------------------------------------------------------------
__global__ __launch_bounds__(512) void partition_kernel(
    const int* __restrict__ erow, const int* __restrict__ ecol,
    const float* __restrict__ eval_, int* __restrict__ cursor,
    int2* __restrict__ ecs, int n_edges) {
    __shared__ int  hist[NBUCK];
    __shared__ int  lbase[NBUCK];
    __shared__ int  gdelta[NBUCK];
    __shared__ int2 data[CHUNK];
    __shared__ int  gpos[CHUNK];
    __shared__ int  wsum[8];

    const int t = threadIdx.x;
    const int base = blockIdx.x * CHUNK;
    const int cnt = min(CHUNK, n_edges - base);

    for (int i = t; i < NBUCK; i += 512) hist[i] = 0;
    __syncthreads();

    int   myrow[CHUNK / 512];
    int   mycol[CHUNK / 512];
    float myval[CHUNK / 512];
    #pragma unroll
    for (int i = 0; i < CHUNK / 512; ++i) {
        const int idx = t + i * 512;
        if (idx < cnt) {
            const int e = base + idx;
            myrow[i] = erow[e];
            mycol[i] = ecol[e];
            myval[i] = eval_[e];
            atomicAdd(&hist[myrow[i] >> 7], 1);
        }
    }
    __syncthreads();

    {
        const int i0 = 2 * t, i1 = 2 * t + 1;
        const int v0 = (i0 < NBUCK) ? hist[i0] : 0;
        const int v1 = (i1 < NBUCK) ? hist[i1] : 0;
        const int s = v0 + v1;
        int inc = s;
        #pragma unroll
        for (int d = 1; d < 64; d <<= 1) {
            int u = __shfl_up(inc, d, 64);
            if ((t & 63) >= d) inc += u;
        }
        if ((t & 63) == 63) wsum[t >> 6] = inc;
        __syncthreads();
        int wp = 0;
        #pragma unroll
        for (int w = 0; w < 8; ++w) if (w < (t >> 6)) wp += wsum[w];
        const int ex = wp + (inc - s);
        if (i0 < NBUCK) lbase[i0] = ex;
        if (i1 < NBUCK) lbase[i1] = ex + v0;
    }
    __syncthreads();

    for (int i = t; i < NBUCK; i += 512) {
        const int c = hist[i];
        gdelta[i] = c ? (atomicAdd(&cursor[i], c) - lbase[i]) : 0;
    }
    __syncthreads();

    #pragma unroll
    for (int i = 0; i < CHUNK / 512; ++i) {
        const int idx = t + i * 512;
        if (idx < cnt) {
            const int bk = myrow[i] >> 7;
            const int slot = atomicAdd(&lbase[bk], 1);
            int2 p;
            p.x = (int)(((unsigned)(myrow[i] & (RPB - 1)) << 25) |
                        ((unsigned)mycol[i] << 7));
            p.y = __float_as_int(myval[i]);
            data[slot] = p;
            gpos[slot] = slot + gdelta[bk];
        }
    }
    __syncthreads();

    for (int slot = t; slot < cnt; slot += 512)
        ecs[gpos[slot]] = data[slot];
}

// ---------------------------------------------------------------------------
// Kernel 5: exact sort within each bucket run (LDS), emitting CSR row_ptr.
// ---------------------------------------------------------------------------
__global__ __launch_bounds__(256) void sort_bucket_kernel(
    const int* __restrict__ bbase, int2* __restrict__ ecs,
    int* __restrict__ row_ptr, int n_nodes) {
    __shared__ int2 data[SCAP];    // 32 KB
    __shared__ int2 data2[SCAP];   // 32 KB
    __shared__ int  hist[RPB];
    __shared__ int  wtot;

    const int bk = blockIdx.x;
    const int t  = threadIdx.x;
    const int s  = bbase[bk];
    const int e  = bbase[bk + 1];
    const int cnt = e - s;
    const int rbase = bk * RPB;

    if (cnt > SCAP) {
        for (int r = t; r < RPB; r += 256)
            if (rbase + r < n_nodes) row_ptr[rbase + r] = INT_MIN;
        return;
    }

    for (int i = t; i < RPB; i += 256) hist[i] = 0;
    __syncthreads();

    for (int i = t; i < cnt; i += 256) {
        const int2 p = ecs[s + i];
        data[i] = p;
        atomicAdd(&hist[((unsigned)p.x) >> 25], 1);
    }
    __syncthreads();

    int inc = 0, v = 0;
    if (t < RPB) {
        v = hist[t];
        inc = v;
        #pragma unroll
        for (int d = 1; d < 64; d <<= 1) {
            int u = __shfl_up(inc, d, 64);
            if ((t & 63) >= d) inc += u;
        }
        if (t == 63) wtot = inc;
    }
    __syncthreads();
    if (t < RPB) {
        if (t >= 64) inc += wtot;
        const int ex = inc - v;
        if (rbase + t < n_nodes) row_ptr[rbase + t] = s + ex;
        hist[t] = ex;
    }
    __syncthreads();

    for (int i = t; i < cnt; i += 256) {
        const int2 p = data[i];
        const int r = (int)(((unsigned)p.x) >> 25);
        const int pos = atomicAdd(&hist[r], 1);
        data2[pos] = p;
    }
    __syncthreads();

    for (int i = t; i < cnt; i += 256) ecs[s + i] = data2[i];
}

// ---------------------------------------------------------------------------
// Kernel 6: gather-aggregate + ReLU, 8 edges per vmem instruction.
// One wave per row. 8 groups of 8 lanes: g = lane>>3 picks the edge,
// q = lane&7 picks the channel octet (half8 = 16B load). Address is one
// v_and_or_b32: (p.x & 0x01FFFF80) | (q<<4). 3-level shfl_xor fold.
// ---------------------------------------------------------------------------
__global__ __launch_bounds__(256) void gather_relu_kernel(
    const __half* __restrict__ xw, const int2* __restrict__ ecs,
    const int* __restrict__ row_ptr, const int* __restrict__ bbase,
    float* __restrict__ out, int n_nodes, int n_edges) {
    const int lane = threadIdx.x & 63;
    const int q    = lane & 7;         // channel octet: chans [8q, 8q+8)
    const int g    = lane >> 3;        // edge subgroup 0..7
    const int r = (blockIdx.x * blockDim.x + threadIdx.x) >> 6;
    if (r >= n_nodes) return;

    const char* xwb = (const char*)xw;
    const int s = row_ptr[r];
    float acc[8];
    #pragma unroll
    for (int i = 0; i < 8; ++i) acc[i] = 0.f;
    const bool ovf = (s == INT_MIN);

    if (ovf) {
        // overflow bucket: filter-scan; every group computes the full sum.
        const int bk = r >> 7;
        const int bs = bbase[bk], be = bbase[bk + 1];
        const unsigned rl = (unsigned)(r & (RPB - 1));
        for (int j = bs; j < be; ++j) {
            const int2 p = ecs[j];
            if ((((unsigned)p.x) >> 25) == rl) {
                const float v = __int_as_float(p.y);
                const unsigned off = (((unsigned)p.x) & 0x01FFFF80u) | ((unsigned)q << 4);
                union { uint4 u; __half2 h[4]; } U;
                U.u = *(const uint4*)(xwb + off);
                #pragma unroll
                for (int i = 0; i < 4; ++i) {
                    const float2 f = __half22float2(U.h[i]);
                    acc[2 * i]     = fmaf(v, f.x, acc[2 * i]);
                    acc[2 * i + 1] = fmaf(v, f.y, acc[2 * i + 1]);
                }
            }
        }
        // no fold: each group already holds the full row sum
    } else {
        const int e2 = row_ptr[r + 1];
        const int e  = (e2 == INT_MIN) ? bbase[(r >> 7) + 1] : e2;
        for (int j = s; j < e; j += 8) {
            const int eidx = j + g;
            const int2 p = ecs[min(eidx, n_edges - 1)];
            const float v = (eidx < e) ? __int_as_float(p.y) : 0.f;
            const unsigned off = (((unsigned)p.x) & 0x01FFFF80u) | ((unsigned)q << 4);
            union { uint4 u; __half2 h[4]; } U;
            U.u = *(const uint4*)(xwb + off);
            #pragma unroll
            for (int i = 0; i < 4; ++i) {
                const float2 f = __half22float2(U.h[i]);
                acc[2 * i]     = fmaf(v, f.x, acc[2 * i]);
                acc[2 * i + 1] = fmaf(v, f.y, acc[2 * i + 1]);
            }
        }
        // fold across the 8 edge-groups (lanes sharing q)
        #pragma unroll
        for (int d = 8; d < 64; d <<= 1)
            #pragma unroll
            for (int i = 0; i < 8; ++i)
                acc[i] += __shfl_xor(acc[i], d, 64);
    }

    if (g == 0) {
        float4 o0, o1;
        o0.x = fmaxf(acc[0], 0.f); o0.y = fmaxf(acc[1], 0.f);
        o0.z = fmaxf(acc[2], 0.f); o0.w = fmaxf(acc[3], 0.f);
        o1.x = fmaxf(acc[4], 0.f); o1.y = fmaxf(acc[5], 0.f);
        o1.z = fmaxf(acc[6], 0.f); o1.w = fmaxf(acc[7], 0.f);
        float* op = out + (size_t)r * OUT_DIM + q * 8;
        *(float4*)(op)     = o0;
        *(float4*)(op + 4) = o1;
    }
}

// ---------------------------------------------------------------------------
// Fallback: atomic scatter path (uses raw edge arrays; unaffected by packing).
// ---------------------------------------------------------------------------
__global__ __launch_bounds__(256) void edge_scatter_kernel(
    const __half* __restrict__ xw, const int* __restrict__ erow,
    const int* __restrict__ ecol, const float* __restrict__ eval_,
    float* __restrict__ out, int n_edges) {
    const int lane  = threadIdx.x & 63;
    const int wid   = (blockIdx.x * blockDim.x + threadIdx.x) >> 6;
    const int nwave = (gridDim.x * blockDim.x) >> 6;
    for (int e = wid; e < n_edges; e += nwave) {
        const float m = eval_[e] * __half2float(xw[(size_t)ecol[e] * OUT_DIM + lane]);
        atomicAdd(&out[(size_t)erow[e] * OUT_DIM + lane], m);
    }
}

__global__ __launch_bounds__(256) void relu_kernel(float4* __restrict__ p, int n4) {
    const int stride = gridDim.x * blockDim.x;
    for (int i = blockIdx.x * blockDim.x + threadIdx.x; i < n4; i += stride) {
        float4 v = p[i];
        v.x = fmaxf(v.x, 0.f); v.y = fmaxf(v.y, 0.f);
        v.z = fmaxf(v.z, 0.f); v.w = fmaxf(v.w, 0.f);
        p[i] = v;
    }
}

extern "C" void kernel_launch(void* const* d_in, const int* in_sizes, int n_in,
                              void* d_out, int out_size, void* d_ws, size_t ws_size,
                              hipStream_t stream) {
    const float* x     = (const float*)d_in[0];
    const int*   erow  = (const int*)d_in[1];
    const int*   ecol  = (const int*)d_in[2];
    const float* eval_ = (const float*)d_in[3];
    const float* W     = (const float*)d_in[4];
    const float* b     = (const float*)d_in[5];
    float*       out   = (float*)d_out;

    const int n_nodes = in_sizes[0] / IN_DIM;
    const int n_edges = in_sizes[1];

    auto align256 = [](size_t v) { return (v + 255) & ~(size_t)255; };
    size_t off_xw     = 0;
    size_t off_wf     = align256(off_xw     + (size_t)n_nodes * OUT_DIM * 2); // fp16 xw
    size_t off_bcount = align256(off_wf     + (size_t)4 * 4 * 64 * 8 * 2);    // fp16 W frags
    size_t off_bbase  = align256(off_bcount + (size_t)NBUCK * 4);
    size_t off_cursor = align256(off_bbase  + (size_t)(NBUCK + 1) * 4);
    size_t off_rowptr = align256(off_cursor + (size_t)NBUCK * 4);
    size_t off_ecs    = align256(off_rowptr + (size_t)(n_nodes + 1) * 4);
    size_t need       = off_ecs + (size_t)n_edges * 8;

    __half* xw = (__half*)((char*)d_ws + off_xw);
    __half* wf = (__half*)((char*)d_ws + off_wf);

    // 1) pre-pack W fragments, then xw = fp16(x @ W + b) via MFMA
    wfrag_kernel<<<1, 256, 0, stream>>>(W, wf);
    gemm_mfma_kernel<<<(n_nodes + 63) / 64, 256, 0, stream>>>(x, wf, b, xw, n_nodes);

    if (need <= ws_size && n_nodes <= NBUCK * RPB && n_edges > 0) {
        int*  bcount = (int*)((char*)d_ws + off_bcount);
        int*  bbase  = (int*)((char*)d_ws + off_bbase);
        int*  cursor = (int*)((char*)d_ws + off_cursor);
        int*  rowptr = (int*)((char*)d_ws + off_rowptr);
        int2* ecs    = (int2*)((char*)d_ws + off_ecs);

        hipMemsetAsync(bcount, 0, (size_t)NBUCK * 4, stream);
        bucket_hist_kernel<<<512, 256, 0, stream>>>(erow, bcount, n_edges);
        bucket_scan_kernel<<<1, 512, 0, stream>>>(bcount, bbase, cursor, rowptr, n_nodes);
        partition_kernel<<<(n_edges + CHUNK - 1) / CHUNK, 512, 0, stream>>>(
            erow, ecol, eval_, cursor, ecs, n_edges);
        sort_bucket_kernel<<<NBUCK, 256, 0, stream>>>(bbase, ecs, rowptr, n_nodes);
        gather_relu_kernel<<<(n_nodes + 3) / 4, 256, 0, stream>>>(
            xw, ecs, rowptr, bbase, out, n_nodes, n_edges);
    } else {
        hipMemsetAsync(d_out, 0, (size_t)out_size * sizeof(float), stream);
        edge_scatter_kernel<<<8192, 256, 0, stream>>>(xw, erow, ecol, eval_, out, n_edges);
        relu_kernel<<<2048, 256, 0, stream>>>((float4*)d_out, out_size / 4);
    }
}

// Round 10
// 121.576 us; speedup vs baseline: 6.6729x; 1.0114x over previous
//
#include <hip/hip_runtime.h>
#include <hip/hip_fp16.h>
#include <limits.h>

#define IN_DIM 128
#define OUT_DIM 64
#define NBUCK 782          // ceil(100000 / 128) row buckets
#define RPB 128            // rows per bucket (row >> 7)
#define CHUNK 4096         // edges per partition block
#define SCAP 4096          // max edges per bucket for LDS sort

// Payload packing: p.x = (rowlocal << 25) | (col << 7)
//  - col<<7 == byte offset of row in fp16 xw; gather addr = (p.x & 0x01FFFF80) | (q<<4)

typedef _Float16 half8_t __attribute__((ext_vector_type(8)));
typedef float    f32x4  __attribute__((ext_vector_type(4)));

__device__ __forceinline__ int kmap(int g, int j) {
    return g * 4 + (j & 3) + 16 * (j >> 2);   // g = lane>>4, j = elem 0..7
}

// ---------------------------------------------------------------------------
// Kernel 0: pre-pack W (fp32 [128][64]) into fragment-ordered fp16 blob.
// ---------------------------------------------------------------------------
__global__ __launch_bounds__(256) void wfrag_kernel(
    const float* __restrict__ W, __half* __restrict__ wf) {
    for (int idx = threadIdx.x; idx < 4 * 4 * 64 * 8; idx += 256) {
        const int j    = idx & 7;
        const int lane = (idx >> 3) & 63;
        const int ks   = (idx >> 9) & 3;
        const int n    = idx >> 11;
        const int col  = n * 16 + (lane & 15);
        const int k    = ks * 32 + kmap(lane >> 4, j);
        wf[idx] = __float2half(W[k * OUT_DIM + col]);
    }
}

// ---------------------------------------------------------------------------
// Kernel 1: xw = fp16(x @ W + b) via MFMA 16x16x32 f16, no LDS.
// ---------------------------------------------------------------------------
__global__ __launch_bounds__(256) void gemm_mfma_kernel(
    const float* __restrict__ x, const __half* __restrict__ wf,
    const float* __restrict__ b, __half* __restrict__ xw, int n_nodes) {
    const int t  = threadIdx.x;
    const int l  = t & 63;
    const int wv = t >> 6;
    const int g  = l >> 4;
    const int rowbase = blockIdx.x * 64 + wv * 16;
    const int row = rowbase + (l & 15);
    const bool rok = row < n_nodes;
    const float* xr = x + (size_t)row * IN_DIM;

    half8_t bf[4][4];   // [n][ks]
    const half8_t* wf8 = (const half8_t*)wf;
    #pragma unroll
    for (int n = 0; n < 4; ++n)
        #pragma unroll
        for (int ks = 0; ks < 4; ++ks)
            bf[n][ks] = wf8[(n * 4 + ks) * 64 + l];

    half8_t af[4];
    #pragma unroll
    for (int ks = 0; ks < 4; ++ks) {
        float4 c0 = rok ? *(const float4*)(xr + ks * 32 + g * 4)
                        : make_float4(0.f, 0.f, 0.f, 0.f);
        float4 c1 = rok ? *(const float4*)(xr + ks * 32 + 16 + g * 4)
                        : make_float4(0.f, 0.f, 0.f, 0.f);
        half8_t a;
        a[0] = (_Float16)c0.x; a[1] = (_Float16)c0.y;
        a[2] = (_Float16)c0.z; a[3] = (_Float16)c0.w;
        a[4] = (_Float16)c1.x; a[5] = (_Float16)c1.y;
        a[6] = (_Float16)c1.z; a[7] = (_Float16)c1.w;
        af[ks] = a;
    }

    f32x4 acc[4];
    #pragma unroll
    for (int n = 0; n < 4; ++n) acc[n] = (f32x4){0.f, 0.f, 0.f, 0.f};

    #pragma unroll
    for (int ks = 0; ks < 4; ++ks)
        #pragma unroll
        for (int n = 0; n < 4; ++n)
            acc[n] = __builtin_amdgcn_mfma_f32_16x16x32_f16(af[ks], bf[n][ks], acc[n], 0, 0, 0);

    float bias[4];
    #pragma unroll
    for (int n = 0; n < 4; ++n) bias[n] = b[n * 16 + (l & 15)];

    // C/D layout (m89-verified): col = lane&15, row = (lane>>4)*4 + reg
    #pragma unroll
    for (int n = 0; n < 4; ++n)
        #pragma unroll
        for (int q = 0; q < 4; ++q) {
            const int ro = rowbase + g * 4 + q;
            if (ro < n_nodes)
                xw[(size_t)ro * OUT_DIM + n * 16 + (l & 15)] =
                    __float2half(acc[n][q] + bias[n]);
        }
}

// ---------------------------------------------------------------------------
// Kernel 2: global bucket histogram (LDS-aggregated). bcount pre-zeroed.
// ---------------------------------------------------------------------------
__global__ __launch_bounds__(256) void bucket_hist_kernel(
    const int* __restrict__ erow, int* __restrict__ bcount, int n_edges) {
    __shared__ int h[NBUCK];
    for (int i = threadIdx.x; i < NBUCK; i += 256) h[i] = 0;
    __syncthreads();
    const int stride = gridDim.x * blockDim.x;
    for (int e = blockIdx.x * blockDim.x + threadIdx.x; e < n_edges; e += stride)
        atomicAdd(&h[erow[e] >> 7], 1);
    __syncthreads();
    for (int i = threadIdx.x; i < NBUCK; i += 256)
        if (h[i]) atomicAdd(&bcount[i], h[i]);
}

// ---------------------------------------------------------------------------
// Kernel 3: exclusive scan of bucket counts (single block, 512 thr, 2/thr).
// ---------------------------------------------------------------------------
__global__ __launch_bounds__(512) void bucket_scan_kernel(
    const int* __restrict__ bcount, int* __restrict__ bbase,
    int* __restrict__ cursor, int* __restrict__ row_ptr, int n_nodes) {
    const int t = threadIdx.x;
    const int i0 = 2 * t, i1 = 2 * t + 1;
    int v0 = (i0 < NBUCK) ? bcount[i0] : 0;
    int v1 = (i1 < NBUCK) ? bcount[i1] : 0;
    const int s = v0 + v1;
    int inc = s;
    #pragma unroll
    for (int d = 1; d < 64; d <<= 1) {
        int u = __shfl_up(inc, d, 64);
        if ((t & 63) >= d) inc += u;
    }
    __shared__ int wsum[8];
    if ((t & 63) == 63) wsum[t >> 6] = inc;
    __syncthreads();
    int wp = 0;
    #pragma unroll
    for (int w = 0; w < 8; ++w) if (w < (t >> 6)) wp += wsum[w];
    const int ex = wp + (inc - s);
    if (i0 < NBUCK) { bbase[i0] = ex;      cursor[i0] = ex; }
    if (i1 < NBUCK) { bbase[i1] = ex + v0; cursor[i1] = ex + v0; }
    if (t == 511) {
        bbase[NBUCK] = wp + inc;
        row_ptr[n_nodes] = wp + inc;
    }
}

// ---------------------------------------------------------------------------
// Kernel 4: partition edges into bucket-grouped ecs[] with run reservation.
// ---------------------------------------------------------------------------
__global__ __launch_bounds__(512) void partition_kernel(
    const int* __restrict__ erow, const int* __restrict__ ecol,
    const float* __restrict__ eval_, int* __restrict__ cursor,
    int2* __restrict__ ecs, int n_edges) {
    __shared__ int  hist[NBUCK];
    __shared__ int  lbase[NBUCK];
    __shared__ int  gdelta[NBUCK];
    __shared__ int2 data[CHUNK];
    __shared__ int  gpos[CHUNK];
    __shared__ int  wsum[8];

    const int t = threadIdx.x;
    const int base = blockIdx.x * CHUNK;
    const int cnt = min(CHUNK, n_edges - base);

    for (int i = t; i < NBUCK; i += 512) hist[i] = 0;
    __syncthreads();

    int   myrow[CHUNK / 512];
    int   mycol[CHUNK / 512];
    float myval[CHUNK / 512];
    #pragma unroll
    for (int i = 0; i < CHUNK / 512; ++i) {
        const int idx = t + i * 512;
        if (idx < cnt) {
            const int e = base + idx;
            myrow[i] = erow[e];
            mycol[i] = ecol[e];
            myval[i] = eval_[e];
            atomicAdd(&hist[myrow[i] >> 7], 1);
        }
    }
    __syncthreads();

    {
        const int i0 = 2 * t, i1 = 2 * t + 1;
        const int v0 = (i0 < NBUCK) ? hist[i0] : 0;
        const int v1 = (i1 < NBUCK) ? hist[i1] : 0;
        const int s = v0 + v1;
        int inc = s;
        #pragma unroll
        for (int d = 1; d < 64; d <<= 1) {
            int u = __shfl_up(inc, d, 64);
            if ((t & 63) >= d) inc += u;
        }
        if ((t & 63) == 63) wsum[t >> 6] = inc;
        __syncthreads();
        int wp = 0;
        #pragma unroll
        for (int w = 0; w < 8; ++w) if (w < (t >> 6)) wp += wsum[w];
        const int ex = wp + (inc - s);
        if (i0 < NBUCK) lbase[i0] = ex;
        if (i1 < NBUCK) lbase[i1] = ex + v0;
    }
    __syncthreads();

    for (int i = t; i < NBUCK; i += 512) {
        const int c = hist[i];
        gdelta[i] = c ? (atomicAdd(&cursor[i], c) - lbase[i]) : 0;
    }
    __syncthreads();

    #pragma unroll
    for (int i = 0; i < CHUNK / 512; ++i) {
        const int idx = t + i * 512;
        if (idx < cnt) {
            const int bk = myrow[i] >> 7;
            const int slot = atomicAdd(&lbase[bk], 1);
            int2 p;
            p.x = (int)(((unsigned)(myrow[i] & (RPB - 1)) << 25) |
                        ((unsigned)mycol[i] << 7));
            p.y = __float_as_int(myval[i]);
            data[slot] = p;
            gpos[slot] = slot + gdelta[bk];
        }
    }
    __syncthreads();

    for (int slot = t; slot < cnt; slot += 512)
        ecs[gpos[slot]] = data[slot];
}

// ---------------------------------------------------------------------------
// Kernel 5: exact sort within each bucket run (LDS), emitting CSR row_ptr.
// ---------------------------------------------------------------------------
__global__ __launch_bounds__(256) void sort_bucket_kernel(
    const int* __restrict__ bbase, int2* __restrict__ ecs,
    int* __restrict__ row_ptr, int n_nodes) {
    __shared__ int2 data[SCAP];    // 32 KB
    __shared__ int2 data2[SCAP];   // 32 KB
    __shared__ int  hist[RPB];
    __shared__ int  wtot;

    const int bk = blockIdx.x;
    const int t  = threadIdx.x;
    const int s  = bbase[bk];
    const int e  = bbase[bk + 1];
    const int cnt = e - s;
    const int rbase = bk * RPB;

    if (cnt > SCAP) {
        for (int r = t; r < RPB; r += 256)
            if (rbase + r < n_nodes) row_ptr[rbase + r] = INT_MIN;
        return;
    }

    for (int i = t; i < RPB; i += 256) hist[i] = 0;
    __syncthreads();

    for (int i = t; i < cnt; i += 256) {
        const int2 p = ecs[s + i];
        data[i] = p;
        atomicAdd(&hist[((unsigned)p.x) >> 25], 1);
    }
    __syncthreads();

    int inc = 0, v = 0;
    if (t < RPB) {
        v = hist[t];
        inc = v;
        #pragma unroll
        for (int d = 1; d < 64; d <<= 1) {
            int u = __shfl_up(inc, d, 64);
            if ((t & 63) >= d) inc += u;
        }
        if (t == 63) wtot = inc;
    }
    __syncthreads();
    if (t < RPB) {
        if (t >= 64) inc += wtot;
        const int ex = inc - v;
        if (rbase + t < n_nodes) row_ptr[rbase + t] = s + ex;
        hist[t] = ex;
    }
    __syncthreads();

    for (int i = t; i < cnt; i += 256) {
        const int2 p = data[i];
        const int r = (int)(((unsigned)p.x) >> 25);
        const int pos = atomicAdd(&hist[r], 1);
        data2[pos] = p;
    }
    __syncthreads();

    for (int i = t; i < cnt; i += 256) ecs[s + i] = data2[i];
}

// ---------------------------------------------------------------------------
// Kernel 6: gather-aggregate + ReLU. TWO rows per wave, batches advanced in
// lock-step so each wave carries 2 independent ecs->xw latency chains.
// 8 edges per vmem instr (g = lane>>3 edge slot, q = lane&7 channel octet).
// ---------------------------------------------------------------------------
__global__ __launch_bounds__(256) void gather_relu_kernel(
    const __half* __restrict__ xw, const int2* __restrict__ ecs,
    const int* __restrict__ row_ptr, const int* __restrict__ bbase,
    float* __restrict__ out, int n_nodes, int n_edges) {
    const int lane = threadIdx.x & 63;
    const int q    = lane & 7;
    const int g    = lane >> 3;
    const int wid  = (blockIdx.x * blockDim.x + threadIdx.x) >> 6;
    const int r0   = wid * 2;
    const int r1   = r0 + 1;
    if (r0 >= n_nodes) return;
    const bool has1 = (r1 < n_nodes);
    const char* xwb = (const char*)xw;

    // resolve row segments (wave-uniform values)
    const int s0raw = row_ptr[r0];
    const int s1raw = has1 ? row_ptr[r1] : INT_MIN;
    const bool ok0 = (s0raw != INT_MIN);
    const bool ok1 = has1 && (s1raw != INT_MIN);

    float acc0[8], acc1[8];
    #pragma unroll
    for (int i = 0; i < 8; ++i) { acc0[i] = 0.f; acc1[i] = 0.f; }

    if (ok0 && (ok1 || !has1)) {
        // common path: both rows (or single last row) normal
        int e0;
        {
            const int n0 = row_ptr[r0 + 1];
            e0 = (n0 == INT_MIN) ? bbase[(r0 >> 7) + 1] : n0;
        }
        int e1 = 0, j1 = 0;
        if (ok1) {
            const int n1 = row_ptr[r1 + 1];
            e1 = (n1 == INT_MIN) ? bbase[(r1 >> 7) + 1] : n1;
            j1 = s1raw;
        }
        int j0 = s0raw;

        while (j0 < e0 || j1 < e1) {
            const bool a0 = j0 < e0;
            const bool a1 = j1 < e1;
            int2 p0, p1; float v0 = 0.f, v1 = 0.f;
            unsigned off0 = 0, off1 = 0;
            if (a0) {
                const int ei = j0 + g;
                p0 = ecs[min(ei, n_edges - 1)];
                v0 = (ei < e0) ? __int_as_float(p0.y) : 0.f;
                off0 = (((unsigned)p0.x) & 0x01FFFF80u) | ((unsigned)q << 4);
            }
            if (a1) {
                const int ei = j1 + g;
                p1 = ecs[min(ei, n_edges - 1)];
                v1 = (ei < e1) ? __int_as_float(p1.y) : 0.f;
                off1 = (((unsigned)p1.x) & 0x01FFFF80u) | ((unsigned)q << 4);
            }
            union { uint4 u; __half2 h[4]; } U0, U1;
            if (a0) U0.u = *(const uint4*)(xwb + off0);
            if (a1) U1.u = *(const uint4*)(xwb + off1);
            if (a0) {
                #pragma unroll
                for (int i = 0; i < 4; ++i) {
                    const float2 f = __half22float2(U0.h[i]);
                    acc0[2 * i]     = fmaf(v0, f.x, acc0[2 * i]);
                    acc0[2 * i + 1] = fmaf(v0, f.y, acc0[2 * i + 1]);
                }
                j0 += 8;
            }
            if (a1) {
                #pragma unroll
                for (int i = 0; i < 4; ++i) {
                    const float2 f = __half22float2(U1.h[i]);
                    acc1[2 * i]     = fmaf(v1, f.x, acc1[2 * i]);
                    acc1[2 * i + 1] = fmaf(v1, f.y, acc1[2 * i + 1]);
                }
                j1 += 8;
            }
        }
    } else {
        // rare overflow path: per-row filter-scan of the bucket run
        #pragma unroll 1
        for (int rr = 0; rr < 2; ++rr) {
            const int r = r0 + rr;
            if (r >= n_nodes) break;
            float* acc = rr ? acc1 : acc0;
            const int sr = row_ptr[r];
            if (sr != INT_MIN) {
                int er;
                const int nr = row_ptr[r + 1];
                er = (nr == INT_MIN) ? bbase[(r >> 7) + 1] : nr;
                for (int j = sr; j < er; j += 8) {
                    const int ei = j + g;
                    const int2 p = ecs[min(ei, n_edges - 1)];
                    const float v = (ei < er) ? __int_as_float(p.y) : 0.f;
                    const unsigned off = (((unsigned)p.x) & 0x01FFFF80u) | ((unsigned)q << 4);
                    union { uint4 u; __half2 h[4]; } U;
                    U.u = *(const uint4*)(xwb + off);
                    #pragma unroll
                    for (int i = 0; i < 4; ++i) {
                        const float2 f = __half22float2(U.h[i]);
                        acc[2 * i]     = fmaf(v, f.x, acc[2 * i]);
                        acc[2 * i + 1] = fmaf(v, f.y, acc[2 * i + 1]);
                    }
                }
            } else {
                const int bk = r >> 7;
                const int bs = bbase[bk], be = bbase[bk + 1];
                const unsigned rl = (unsigned)(r & (RPB - 1));
                for (int j = bs; j < be; ++j) {
                    const int2 p = ecs[j];
                    if ((((unsigned)p.x) >> 25) == rl) {
                        const float v = __int_as_float(p.y);
                        const unsigned off = (((unsigned)p.x) & 0x01FFFF80u) | ((unsigned)q << 4);
                        union { uint4 u; __half2 h[4]; } U;
                        U.u = *(const uint4*)(xwb + off);
                        #pragma unroll
                        for (int i = 0; i < 4; ++i) {
                            const float2 f = __half22float2(U.h[i]);
                            // filter-scan: all groups compute full sum; scale by 1/8
                            acc[2 * i]     = fmaf(v * 0.125f, f.x, acc[2 * i]);
                            acc[2 * i + 1] = fmaf(v * 0.125f, f.y, acc[2 * i + 1]);
                        }
                    }
                }
                // multiply back by 8 after fold (fold sums 8 identical copies)
                #pragma unroll
                for (int i = 0; i < 8; ++i) acc[i] *= 1.0f;  // handled by fold
            }
        }
    }

    // fold across the 8 edge-groups (lanes sharing q) for both rows
    #pragma unroll
    for (int d = 8; d < 64; d <<= 1) {
        #pragma unroll
        for (int i = 0; i < 8; ++i) {
            acc0[i] += __shfl_xor(acc0[i], d, 64);
            acc1[i] += __shfl_xor(acc1[i], d, 64);
        }
    }

    if (g == 0) {
        {
            float4 o0, o1;
            o0.x = fmaxf(acc0[0], 0.f); o0.y = fmaxf(acc0[1], 0.f);
            o0.z = fmaxf(acc0[2], 0.f); o0.w = fmaxf(acc0[3], 0.f);
            o1.x = fmaxf(acc0[4], 0.f); o1.y = fmaxf(acc0[5], 0.f);
            o1.z = fmaxf(acc0[6], 0.f); o1.w = fmaxf(acc0[7], 0.f);
            float* op = out + (size_t)r0 * OUT_DIM + q * 8;
            *(float4*)(op)     = o0;
            *(float4*)(op + 4) = o1;
        }
        if (has1) {
            float4 o0, o1;
            o0.x = fmaxf(acc1[0], 0.f); o0.y = fmaxf(acc1[1], 0.f);
            o0.z = fmaxf(acc1[2], 0.f); o0.w = fmaxf(acc1[3], 0.f);
            o1.x = fmaxf(acc1[4], 0.f); o1.y = fmaxf(acc1[5], 0.f);
            o1.z = fmaxf(acc1[6], 0.f); o1.w = fmaxf(acc1[7], 0.f);
            float* op = out + (size_t)r1 * OUT_DIM + q * 8;
            *(float4*)(op)     = o0;
            *(float4*)(op + 4) = o1;
        }
    }
}

// ---------------------------------------------------------------------------
// Fallback: atomic scatter path (uses raw edge arrays; unaffected by packing).
// ---------------------------------------------------------------------------
__global__ __launch_bounds__(256) void edge_scatter_kernel(
    const __half* __restrict__ xw, const int* __restrict__ erow,
    const int* __restrict__ ecol, const float* __restrict__ eval_,
    float* __restrict__ out, int n_edges) {
    const int lane  = threadIdx.x & 63;
    const int wid   = (blockIdx.x * blockDim.x + threadIdx.x) >> 6;
    const int nwave = (gridDim.x * blockDim.x) >> 6;
    for (int e = wid; e < n_edges; e += nwave) {
        const float m = eval_[e] * __half2float(xw[(size_t)ecol[e] * OUT_DIM + lane]);
        atomicAdd(&out[(size_t)erow[e] * OUT_DIM + lane], m);
    }
}

__global__ __launch_bounds__(256) void relu_kernel(float4* __restrict__ p, int n4) {
    const int stride = gridDim.x * blockDim.x;
    for (int i = blockIdx.x * blockDim.x + threadIdx.x; i < n4; i += stride) {
        float4 v = p[i];
        v.x = fmaxf(v.x, 0.f); v.y = fmaxf(v.y, 0.f);
        v.z = fmaxf(v.z, 0.f); v.w = fmaxf(v.w, 0.f);
        p[i] = v;
    }
}

extern "C" void kernel_launch(void* const* d_in, const int* in_sizes, int n_in,
                              void* d_out, int out_size, void* d_ws, size_t ws_size,
                              hipStream_t stream) {
    const float* x     = (const float*)d_in[0];
    const int*   erow  = (const int*)d_in[1];
    const int*   ecol  = (const int*)d_in[2];
    const float* eval_ = (const float*)d_in[3];
    const float* W     = (const float*)d_in[4];
    const float* b     = (const float*)d_in[5];
    float*       out   = (float*)d_out;

    const int n_nodes = in_sizes[0] / IN_DIM;
    const int n_edges = in_sizes[1];

    auto align256 = [](size_t v) { return (v + 255) & ~(size_t)255; };
    size_t off_xw     = 0;
    size_t off_wf     = align256(off_xw     + (size_t)n_nodes * OUT_DIM * 2); // fp16 xw
    size_t off_bcount = align256(off_wf     + (size_t)4 * 4 * 64 * 8 * 2);    // fp16 W frags
    size_t off_bbase  = align256(off_bcount + (size_t)NBUCK * 4);
    size_t off_cursor = align256(off_bbase  + (size_t)(NBUCK + 1) * 4);
    size_t off_rowptr = align256(off_cursor + (size_t)NBUCK * 4);
    size_t off_ecs    = align256(off_rowptr + (size_t)(n_nodes + 1) * 4);
    size_t need       = off_ecs + (size_t)n_edges * 8;

    __half* xw = (__half*)((char*)d_ws + off_xw);
    __half* wf = (__half*)((char*)d_ws + off_wf);

    // 1) pre-pack W fragments, then xw = fp16(x @ W + b) via MFMA
    wfrag_kernel<<<1, 256, 0, stream>>>(W, wf);
    gemm_mfma_kernel<<<(n_nodes + 63) / 64, 256, 0, stream>>>(x, wf, b, xw, n_nodes);

    if (need <= ws_size && n_nodes <= NBUCK * RPB && n_edges > 0) {
        int*  bcount = (int*)((char*)d_ws + off_bcount);
        int*  bbase  = (int*)((char*)d_ws + off_bbase);
        int*  cursor = (int*)((char*)d_ws + off_cursor);
        int*  rowptr = (int*)((char*)d_ws + off_rowptr);
        int2* ecs    = (int2*)((char*)d_ws + off_ecs);

        hipMemsetAsync(bcount, 0, (size_t)NBUCK * 4, stream);
        bucket_hist_kernel<<<512, 256, 0, stream>>>(erow, bcount, n_edges);
        bucket_scan_kernel<<<1, 512, 0, stream>>>(bcount, bbase, cursor, rowptr, n_nodes);
        partition_kernel<<<(n_edges + CHUNK - 1) / CHUNK, 512, 0, stream>>>(
            erow, ecol, eval_, cursor, ecs, n_edges);
        sort_bucket_kernel<<<NBUCK, 256, 0, stream>>>(bbase, ecs, rowptr, n_nodes);
        gather_relu_kernel<<<(n_nodes + 7) / 8, 256, 0, stream>>>(
            xw, ecs, rowptr, bbase, out, n_nodes, n_edges);
    } else {
        hipMemsetAsync(d_out, 0, (size_t)out_size * sizeof(float), stream);
        edge_scatter_kernel<<<8192, 256, 0, stream>>>(xw, erow, ecol, eval_, out, n_edges);
        relu_kernel<<<2048, 256, 0, stream>>>((float4*)d_out, out_size / 4);
    }
}